// Round 11
// baseline (482.719 us; speedup 1.0000x reference)
//
#include <hip/hip_runtime.h>
#include <hip/hip_cooperative_groups.h>

namespace cg = cooperative_groups;

// ---------- common helpers ----------
typedef __bf16 bf16x8 __attribute__((ext_vector_type(8)));
typedef float f32x4 __attribute__((ext_vector_type(4)));

__device__ __forceinline__ float b2f(ushort u) {
    union { unsigned int i; float f; } v;
    v.i = ((unsigned int)u) << 16;
    return v.f;
}
__device__ __forceinline__ ushort f2b(float f) {
    union { float f; unsigned int i; } v;
    v.f = f;
    unsigned int x = v.i;
    unsigned int r = (x + 0x7fffu + ((x >> 16) & 1u)) >> 16;
    return (ushort)r;
}
__device__ __forceinline__ float fexp2(float x) {
#if __has_builtin(__builtin_amdgcn_exp2f)
    return __builtin_amdgcn_exp2f(x);
#else
    return exp2f(x);
#endif
}
// pack (ap,h) as bf16 pair: lo=ap, hi=h
__device__ __forceinline__ unsigned int packb2(float ap, float h) {
    return ((unsigned int)f2b(h) << 16) | (unsigned int)f2b(ap);
}
// async 16B global->LDS; lane i lands at lds + i*16B (wave-uniform base)
__device__ __forceinline__ void gload16(const ushort* g, ushort* l) {
    __builtin_amdgcn_global_load_lds(
        (const __attribute__((address_space(1))) unsigned int*)g,
        (__attribute__((address_space(3))) unsigned int*)l, 16, 0, 0);
}
// LDS fragment read with XOR chunk swizzle (row stride 64 ushorts, 8 chunks of 8)
__device__ __forceinline__ bf16x8 ldsfrag(const ushort* s, int row, int cq) {
    int p = cq ^ (row & 7);
    return *(const bf16x8*)(s + row * 64 + p * 8);
}

#define D_MODEL 1024
#define D_INNER 2048
#define D_STATE 16
#define DT_RANK 64
#define NTOK    2048   // B*L
#define LSEQ    1024
#define NCH     64     // scan chunks (64: 4 blocks/CU for latency hiding)
#define LC      16     // steps per chunk
#define KSL     16     // xproj K-slices
#define LOG2E   1.44269504088896f

// ---------- K0: prep = RMSNorm + weight cvts + xdbl zero + out zero ----------
__global__ __launch_bounds__(256) void prep_kernel(
    const float* __restrict__ hs, const float* __restrict__ w,
    ushort* __restrict__ hout, float* __restrict__ resid,
    const float* __restrict__ inproj, const float* __restrict__ outproj,
    const float* __restrict__ xprojw, const float* __restrict__ dtw,
    ushort* __restrict__ wIn, ushort* __restrict__ wOut,
    ushort* __restrict__ xpw, ushort* __restrict__ dtwb,
    float* __restrict__ xdbl, float* __restrict__ outz)
{
    int blk = blockIdx.x;
    int tid = threadIdx.x;
    if (blk < NTOK) {
        int t = blk;
        float4 r4 = *(const float4*)(hs + (size_t)t * D_MODEL + tid * 4);
        float s = r4.x * r4.x + r4.y * r4.y + r4.z * r4.z + r4.w * r4.w;
        #pragma unroll
        for (int off = 32; off >= 1; off >>= 1) s += __shfl_xor(s, off);
        __shared__ float red[4];
        int lane = tid & 63, wid = tid >> 6;
        if (lane == 0) red[wid] = s;
        __syncthreads();
        float tot = red[0] + red[1] + red[2] + red[3];
        float inv = 1.0f / (sqrtf(tot) * (1.0f / 32.0f) + 1e-5f);
        float4 w4 = *(const float4*)(w + tid * 4);
        ushort4 o;
        o.x = f2b(w4.x * r4.x * inv);
        o.y = f2b(w4.y * r4.y * inv);
        o.z = f2b(w4.z * r4.z * inv);
        o.w = f2b(w4.w * r4.w * inv);
        *(ushort4*)(hout + (size_t)t * D_MODEL + tid * 4) = o;
        *(float4*)(resid + (size_t)t * D_MODEL + tid * 4) = r4;   // exact copy
    } else if (blk < NTOK + 6464) {
        int i = (blk - NTOK) * 256 + tid;
        const float* src; ushort* dst; int off;
        if (i < 1048576)      { src = inproj;  dst = wIn;  off = i; }
        else if (i < 1572864) { src = outproj; dst = wOut; off = i - 1048576; }
        else if (i < 1622016) { src = xprojw;  dst = xpw;  off = i - 1572864; }
        else if (i < 1654784) { src = dtw;     dst = dtwb; off = i - 1622016; }
        else return;
        float4 v = *(const float4*)(src + (size_t)off * 4);
        ushort4 o;
        o.x = f2b(v.x); o.y = f2b(v.y); o.z = f2b(v.z); o.w = f2b(v.w);
        *(ushort4*)(dst + (size_t)off * 4) = o;
    } else if (blk < NTOK + 6464 + 192) {
        int i = (blk - NTOK - 6464) * 256 + tid;   // 49152 float4s = 196608 floats
        if (i < 49152)
            *(float4*)(xdbl + (size_t)i * 4) = (float4){0.f, 0.f, 0.f, 0.f};
    } else {
        int i = (blk - NTOK - 6464 - 192) * 256 + tid;  // 524288 float4s = out f32
        if (i < 524288)
            *(float4*)(outz + (size_t)i * 4) = (float4){0.f, 0.f, 0.f, 0.f};
    }
}

// ---------- K2: xz GEMM 128x128, 8 waves (512 thr), fused conv/SiLU epilogue ----------
// bn<16: x-half -> conv+SiLU rows 3..127 written to xcb; raw boundary rows
//        {0,1,2,125,126,127} saved to xb for the fixup kernel.
// bn>=16: z-half -> plain bf16 store to zq (LDS-repack coalesced).
// 8 waves/block -> 2 blocks/CU = 4 waves/SIMD: hides barrier drain.
__global__ __launch_bounds__(512) void gemm_xz_kernel(
    const ushort* __restrict__ Ag, const ushort* __restrict__ Wg,
    const float* __restrict__ cw, const float* __restrict__ cb,
    ushort* __restrict__ xcb, ushort* __restrict__ xb,
    ushort* __restrict__ zq, int K)
{
    __shared__ __align__(16) ushort smem[128 * 128];   // 32KB: staging + C repack
    __shared__ float cwl[128][4];
    __shared__ float cbl[128];
    ushort* sA = smem;
    ushort* sB = smem + 128 * 64;
    int tid = threadIdx.x;
    int bm = blockIdx.x, bn = blockIdx.y;
    int wid = tid >> 6, lane = tid & 63;
    int wm = (wid >> 1) * 32, wn = (wid & 1) * 64;   // wave owns 32x64
    int l16 = lane & 15, q = lane >> 4;
    int colbase = (bn & 15) * 128;

    if (bn < 16 && tid < 128) {            // stage conv weights for this col range
        cwl[tid][0] = cw[(size_t)(colbase + tid) * 4 + 0];
        cwl[tid][1] = cw[(size_t)(colbase + tid) * 4 + 1];
        cwl[tid][2] = cw[(size_t)(colbase + tid) * 4 + 2];
        cwl[tid][3] = cw[(size_t)(colbase + tid) * 4 + 3];
        cbl[tid] = cb[colbase + tid];
    }

    f32x4 acc[2][4];
    #pragma unroll
    for (int i = 0; i < 2; i++)
        #pragma unroll
        for (int j = 0; j < 4; j++)
            acc[i][j] = (f32x4){0.f, 0.f, 0.f, 0.f};

    const ushort* Abase = Ag + (size_t)bm * 128 * K;
    const ushort* Wbase = Wg + (size_t)bn * 128 * K;

    int segr = lane >> 3, segc = lane & 7;
    size_t goff[2]; int sseg[2];
    #pragma unroll
    for (int t = 0; t < 2; t++) {          // 16 segs each for A and B, 8 wids x 2
        int s = wid * 2 + t;
        int r = s * 8 + segr;
        int gc = segc ^ (r & 7);
        sseg[t] = s * 512;
        goff[t] = (size_t)r * K + gc * 8;
    }

    for (int k0 = 0; k0 < K; k0 += 64) {
        __syncthreads();
        #pragma unroll
        for (int t = 0; t < 2; t++) {
            gload16(Abase + goff[t] + k0, sA + sseg[t]);
            gload16(Wbase + goff[t] + k0, sB + sseg[t]);
        }
        __syncthreads();
        #pragma unroll
        for (int ks = 0; ks < 2; ks++) {
            int cq = ks * 4 + q;
            bf16x8 af[2], bfr[4];
            #pragma unroll
            for (int i = 0; i < 2; i++)
                af[i] = ldsfrag(sA, wm + i * 16 + l16, cq);
            #pragma unroll
            for (int j = 0; j < 4; j++)
                bfr[j] = ldsfrag(sB, wn + j * 16 + l16, cq);
            #pragma unroll
            for (int i = 0; i < 2; i++)
                #pragma unroll
                for (int j = 0; j < 4; j++)
                    acc[i][j] = __builtin_amdgcn_mfma_f32_16x16x32_bf16(af[i], bfr[j], acc[i][j], 0, 0, 0);
        }
    }

    // repack bf16 C tile into LDS (chunk-XOR vs row to spread banks)
    __syncthreads();
    #pragma unroll
    for (int i = 0; i < 2; i++)
        #pragma unroll
        for (int j = 0; j < 4; j++) {
            int col = wn + j * 16 + l16;
            int cchunk = col >> 3, cin = col & 7;
            #pragma unroll
            for (int r = 0; r < 4; r++) {
                int row = wm + i * 16 + q * 4 + r;
                smem[row * 128 + ((cchunk ^ (row & 7)) << 3) + cin] =
                    f2b(acc[i][j][r]);
            }
        }
    __syncthreads();
    size_t rowbase = (size_t)bm * 128;

    if (bn >= 16) {                        // z-half: plain coalesced store
        int cb2 = (bn - 16) * 128;
        #pragma unroll
        for (int it = 0; it < 4; it++) {
            int flat = it * 4096 + tid * 8;
            int row = flat >> 7, cchunk = (flat & 127) >> 3;
            *(uint4*)(zq + (rowbase + row) * D_INNER + cb2 + (cchunk << 3)) =
                *(const uint4*)(smem + row * 128 + ((cchunk ^ (row & 7)) << 3));
        }
        return;
    }

    // x-half: save raw boundary rows {0,1,2,125,126,127} for the fixup kernel
    if (tid < 96) {
        int rr = tid >> 4;                 // 0..5
        int row = (rr < 3) ? rr : (125 + rr - 3);
        int chunk = tid & 15;
        *(uint4*)(xb + (size_t)(bm * 6 + rr) * D_INNER + colbase + chunk * 8) =
            *(const uint4*)(smem + row * 128 + ((chunk ^ (row & 7)) << 3));
    }

    // fused conv+SiLU for rows 3..127 (l>=3 guaranteed: l=(bm&7)*128+row)
    for (int idx = tid; idx < 2000; idx += 512) {
        int row = (idx >> 4) + 3;
        int chunk = idx & 15;
        ushort tap[4][8];
        #pragma unroll
        for (int k = 0; k < 4; k++) {
            int rk = row - 3 + k;
            *(uint4*)tap[k] =
                *(const uint4*)(smem + rk * 128 + ((chunk ^ (rk & 7)) << 3));
        }
        ushort o[8];
        #pragma unroll
        for (int j = 0; j < 8; j++) {
            int cl = chunk * 8 + j;
            float acc2 = cbl[cl];
            #pragma unroll
            for (int k = 0; k < 4; k++)
                acc2 += b2f(tap[k][j]) * cwl[cl][k];
            o[j] = f2b(acc2 / (1.f + __expf(-acc2)));
        }
        *(uint4*)(xcb + (rowbase + row) * D_INNER + colbase + chunk * 8) =
            *(const uint4*)o;
    }
}

// ---------- K2b: conv fixup for rows 0..2 of each 128-token tile (48 tokens) ----------
__global__ __launch_bounds__(256) void conv_fixup_kernel(
    const ushort* __restrict__ xb, const float* __restrict__ cw,
    const float* __restrict__ cb, ushort* __restrict__ xcb)
{
    int bm = blockIdx.x / 3;               // 0..15
    int r  = blockIdx.x % 3;               // 0..2
    int d0 = threadIdx.x * 8;

    ushort tap[4][8];
    bool has[4];
    #pragma unroll
    for (int k = 0; k < 4; k++) {
        int rt = r - 3 + k;                // token offset within tile, may be <0
        if (rt < 0 && (bm & 7) == 0) {     // l = r here -> causal zero-pad
            has[k] = false;
        } else {
            has[k] = true;
            int bmm, slot;
            if (rt < 0) { bmm = bm - 1; slot = rt + 6; }   // prev rows 125..127 -> 3..5
            else        { bmm = bm;     slot = rt; }       // own rows 0..2
            *(uint4*)tap[k] =
                *(const uint4*)(xb + (size_t)(bmm * 6 + slot) * D_INNER + d0);
        }
    }
    ushort o[8];
    #pragma unroll
    for (int j = 0; j < 8; j++) {
        float4 w4 = *(const float4*)(cw + (size_t)(d0 + j) * 4);
        float wk[4] = {w4.x, w4.y, w4.z, w4.w};
        float acc = cb[d0 + j];
        #pragma unroll
        for (int k = 0; k < 4; k++)
            if (has[k]) acc += b2f(tap[k][j]) * wk[k];
        o[j] = f2b(acc / (1.f + __expf(-acc)));
    }
    *(uint4*)(xcb + (size_t)(bm * 128 + r) * D_INNER + d0) = *(const uint4*)o;
}

// ---------- K6: 64x64 GEMM, split-K=2 (4 blocks/CU), f32 atomic epilogue ----------
__global__ __launch_bounds__(256) void gemm64_kernel(
    const ushort* __restrict__ Ag, const ushort* __restrict__ Wg,
    float* __restrict__ Cf, int M, int N, int K)
{
    __shared__ __align__(16) ushort sA[64 * 64];
    __shared__ __align__(16) ushort sB[64 * 64];
    int tid = threadIdx.x;
    int bm = blockIdx.x, bn = blockIdx.y, bz = blockIdx.z;
    int wid = tid >> 6, lane = tid & 63;
    int wm = wid * 16;
    int l16 = lane & 15, q = lane >> 4;

    f32x4 acc[4];
    #pragma unroll
    for (int j = 0; j < 4; j++) acc[j] = (f32x4){0.f, 0.f, 0.f, 0.f};

    const ushort* Abase = Ag + (size_t)bm * 64 * K;
    const ushort* Wbase = Wg + (size_t)bn * 64 * K;

    int segr = lane >> 3, segc = lane & 7;
    size_t goff[2]; int sseg[2];
    #pragma unroll
    for (int t = 0; t < 2; t++) {
        int s = wid * 2 + t;
        int r = s * 8 + segr;
        int gc = segc ^ (r & 7);
        sseg[t] = s * 512;
        goff[t] = (size_t)r * K + gc * 8;
    }

    int kbeg = bz * (K / 2), kend = kbeg + K / 2;
    for (int k0 = kbeg; k0 < kend; k0 += 64) {
        __syncthreads();
        #pragma unroll
        for (int t = 0; t < 2; t++) {
            gload16(Abase + goff[t] + k0, sA + sseg[t]);
            gload16(Wbase + goff[t] + k0, sB + sseg[t]);
        }
        __syncthreads();
        #pragma unroll
        for (int ks = 0; ks < 2; ks++) {
            int cq = ks * 4 + q;
            bf16x8 af = ldsfrag(sA, wm + l16, cq);
            bf16x8 bfr[4];
            #pragma unroll
            for (int j = 0; j < 4; j++)
                bfr[j] = ldsfrag(sB, j * 16 + l16, cq);
            #pragma unroll
            for (int j = 0; j < 4; j++)
                acc[j] = __builtin_amdgcn_mfma_f32_16x16x32_bf16(af, bfr[j], acc[j], 0, 0, 0);
        }
    }

    int row0 = bm * 64 + wm + q * 4;
    int col0 = bn * 64 + l16;
    #pragma unroll
    for (int j = 0; j < 4; j++)
        #pragma unroll
        for (int r = 0; r < 4; r++)
            atomicAdd(&Cf[(size_t)(row0 + r) * N + col0 + j * 16], acc[j][r]);
}

// ---------- K4a: xproj split-K partial GEMM, 64-row tiles (2 blocks/CU) ----------
// LDS row stride 40 ushorts (80B, 16B-aligned): ~2-way banks vs 8-way at 32
__global__ __launch_bounds__(256) void xproj_partial_kernel(
    const ushort* __restrict__ xcb, const ushort* __restrict__ wq,
    float* __restrict__ xdbl)
{
    __shared__ __align__(16) ushort sA[64 * 40];
    __shared__ __align__(16) ushort sB[96 * 40];
    int tid = threadIdx.x;
    int bm = blockIdx.x, sl = blockIdx.y;    // bm<32 (64-row tiles), sl<16
    int wid = tid >> 6, lane = tid & 63;
    int wm = wid * 16;
    int l16 = lane & 15, q = lane >> 4;

    f32x4 acc[6];
    #pragma unroll
    for (int j = 0; j < 6; j++)
        acc[j] = (f32x4){0.f, 0.f, 0.f, 0.f};

    const ushort* Abase = xcb + (size_t)bm * 64 * D_INNER;
    int kbase = sl * (D_INNER / KSL);

    for (int kk = 0; kk < D_INNER / KSL; kk += 32) {
        int k0 = kbase + kk;
        __syncthreads();
        {
            int r = tid >> 2, c = (tid & 3) << 3;   // 256 uint4 = 64 rows x 32 cols
            *(uint4*)(sA + r * 40 + c) = *(const uint4*)(Abase + (size_t)r * D_INNER + k0 + c);
        }
        for (int i = tid; i < 384; i += 256) {
            int r = i >> 2, c = (i & 3) << 3;
            *(uint4*)(sB + r * 40 + c) = *(const uint4*)(wq + (size_t)r * D_INNER + k0 + c);
        }
        __syncthreads();
        bf16x8 af = *(const bf16x8*)(sA + (wm + l16) * 40 + q * 8);
        bf16x8 bfr[6];
        #pragma unroll
        for (int j = 0; j < 6; j++)
            bfr[j] = *(const bf16x8*)(sB + (j * 16 + l16) * 40 + q * 8);
        #pragma unroll
        for (int j = 0; j < 6; j++)
            acc[j] = __builtin_amdgcn_mfma_f32_16x16x32_bf16(af, bfr[j], acc[j], 0, 0, 0);
    }

    int row0 = bm * 64 + wm + q * 4;
    #pragma unroll
    for (int j = 0; j < 6; j++)
        #pragma unroll
        for (int r = 0; r < 4; r++)
            atomicAdd(&xdbl[(size_t)(row0 + r) * 96 + j * 16 + l16], acc[j][r]);
}

// ---------- K4b: dt = softplus(xdbl[:, :64] @ dt_proj_w^T + b) -> bf16 ----------
__global__ __launch_bounds__(256) void dt_gemm_kernel(
    const float* __restrict__ xdbl, const ushort* __restrict__ dtwq,
    const float* __restrict__ dtb, ushort* __restrict__ dtout)
{
    __shared__ __align__(16) ushort sA[64 * 72];
    __shared__ __align__(16) ushort sB[64 * 72];
    int tid = threadIdx.x;
    int bm = blockIdx.x, bn = blockIdx.y;
    int wid = tid >> 6, lane = tid & 63;
    int wm = wid * 16;
    int l16 = lane & 15, q = lane >> 4;

    const float* Abase = xdbl + (size_t)bm * 64 * 96;
    const ushort* Bbase = dtwq + (size_t)bn * 64 * DT_RANK;
    #pragma unroll
    for (int i = tid; i < 512; i += 256) {
        int r = i >> 3, c = (i & 7) << 3;
        float4 v0 = *(const float4*)(Abase + (size_t)r * 96 + c);
        float4 v1 = *(const float4*)(Abase + (size_t)r * 96 + c + 4);
        ushort o[8] = {f2b(v0.x), f2b(v0.y), f2b(v0.z), f2b(v0.w),
                       f2b(v1.x), f2b(v1.y), f2b(v1.z), f2b(v1.w)};
        *(uint4*)(sA + r * 72 + c) = *(const uint4*)o;
        *(uint4*)(sB + r * 72 + c) = *(const uint4*)(Bbase + (size_t)r * DT_RANK + c);
    }
    __syncthreads();

    f32x4 acc[4];
    #pragma unroll
    for (int j = 0; j < 4; j++) acc[j] = (f32x4){0.f, 0.f, 0.f, 0.f};

    #pragma unroll
    for (int ks = 0; ks < 2; ks++) {
        bf16x8 af = *(const bf16x8*)(sA + (wm + l16) * 72 + ks * 32 + q * 8);
        bf16x8 bfr[4];
        #pragma unroll
        for (int j = 0; j < 4; j++)
            bfr[j] = *(const bf16x8*)(sB + (j * 16 + l16) * 72 + ks * 32 + q * 8);
        #pragma unroll
        for (int j = 0; j < 4; j++)
            acc[j] = __builtin_amdgcn_mfma_f32_16x16x32_bf16(af, bfr[j], acc[j], 0, 0, 0);
    }

    __syncthreads();
    #pragma unroll
    for (int j = 0; j < 4; j++) {
        float bias = dtb[bn * 64 + j * 16 + l16];
        #pragma unroll
        for (int r = 0; r < 4; r++) {
            float s = acc[j][r] + bias;
            float sp = (s > 20.f) ? s : log1pf(__expf(s));
            sA[(wm + q * 4 + r) * 72 + j * 16 + l16] = f2b(sp);
        }
    }
    __syncthreads();
    int row0 = bm * 64, col0 = bn * 64;
    #pragma unroll
    for (int rep = 0; rep < 2; rep++) {
        int off = rep * 2048 + tid * 8;
        int row = off >> 6, col = off & 63;
        *(uint4*)(dtout + (size_t)(row0 + row) * D_INNER + col0 + col) =
            *(const uint4*)(sA + row * 72 + col);
    }
}

// ---------- K5: fused scan (A + stitch + C) — cooperative, 1024 blocks ----------
// Phase A: per-chunk local scan -> packed (ap,h) in ch.
// Phase B (first 256 blocks): serial stitch -> bf16 h_init.
// Phase C: re-scan with h_init, fused C-proj + D-skip + gate -> yg.
// sBC tile and A[16]/Dd stay live across grid.sync() (same block, same chunk).
__global__ __launch_bounds__(256, 4) void scan_fused_kernel(
    const ushort* __restrict__ dt, const ushort* __restrict__ xcq,
    const float* __restrict__ xdbl, const ushort* __restrict__ zq,
    const float* __restrict__ Alog, const float* __restrict__ Dp,
    unsigned int* __restrict__ ch, ushort* __restrict__ hinit,
    ushort* __restrict__ yg)
{
    cg::grid_group grid = cg::this_grid();
    __shared__ float sBC[LC][32];
    int bid = blockIdx.x;                  // 1024 = b(2) x chunk(64) x dgroup(8)
    int g = bid & 7;
    int c = (bid >> 3) & (NCH - 1);
    int b = bid >> 9;
    int tid = threadIdx.x;
    int lane = tid & 63, wid = tid >> 6;
    int d = g * 256 + wid * 64 + lane;
    int l0 = c * LC;

    if (tid < LC * 8) {                    // stage B/C tile (16 rows x 32 floats)
        int r = tid >> 3, c4 = (tid & 7) * 4;
        *(float4*)&sBC[r][c4] =
            *(const float4*)(xdbl + ((size_t)(b * LSEQ + l0 + r)) * 96 + 64 + c4);
    }
    float A[16];
    #pragma unroll
    for (int k = 0; k < 4; k++)
        *(float4*)&A[k * 4] = *(const float4*)(Alog + d * D_STATE + k * 4);
    #pragma unroll
    for (int n = 0; n < 16; n++) A[n] = -__expf(A[n]) * LOG2E;
    float Dd = Dp[d];
    __syncthreads();

    const ushort* dtp = dt  + ((size_t)(b * LSEQ + l0)) * D_INNER + d;
    const ushort* xcp = xcq + ((size_t)(b * LSEQ + l0)) * D_INNER + d;

    // ---- phase A ----
    {
        float h[16];
        #pragma unroll
        for (int n = 0; n < 16; n++) h[n] = 0.f;
        float S = 0.f;                     // sum of dtv; prod a = exp2(A*S)
        for (int l = 0; l < LC; l++) {
            float dtv = b2f(dtp[(size_t)l * D_INNER]);
            float xcv = b2f(xcp[(size_t)l * D_INNER]);
            float t = dtv * xcv;
            S += dtv;
            float Bv[16];
            #pragma unroll
            for (int k = 0; k < 4; k++)
                *(float4*)&Bv[k * 4] = *(const float4*)&sBC[l][k * 4];
            #pragma unroll
            for (int n = 0; n < 16; n++) {
                float a = fexp2(dtv * A[n]);
                h[n] = h[n] * a + t * Bv[n];
            }
        }
        unsigned int* outp = ch + (((size_t)(c * 2 + b)) << 15) + (d << 4);
        #pragma unroll
        for (int n = 0; n < 16; n += 4) {
            uint4 v;
            v.x = packb2(fexp2(A[n] * S),     h[n]);
            v.y = packb2(fexp2(A[n + 1] * S), h[n + 1]);
            v.z = packb2(fexp2(A[n + 2] * S), h[n + 2]);
            v.w = packb2(fexp2(A[n + 3] * S), h[n + 3]);
            *(uint4*)&outp[n] = v;
        }
    }

    grid.sync();

    // ---- phase B: stitch (first 256 blocks = 65536 threads) ----
    if (bid < 256) {
        int kk = bid * 256 + tid;          // b(2) x dn(32768)
        int bb = kk >> 15, dn = kk & 32767;
        float run = 0.f;
        #pragma unroll 8
        for (int c2 = 0; c2 < NCH; c2++) {
            size_t off = (((size_t)(c2 * 2 + bb)) << 15) + dn;
            unsigned int v = ch[off];
            hinit[off] = f2b(run);
            run = b2f((ushort)(v & 0xffffu)) * run + b2f((ushort)(v >> 16));
        }
    }

    grid.sync();

    // ---- phase C: full scan with h_init, fused output ----
    {
        const ushort* hp = hinit + (((size_t)(c * 2 + b)) << 15) + (d << 4);
        float h[16];
        #pragma unroll
        for (int n = 0; n < 16; n += 4) {
            ushort4 v = *(const ushort4*)(hp + n);
            h[n] = b2f(v.x); h[n + 1] = b2f(v.y);
            h[n + 2] = b2f(v.z); h[n + 3] = b2f(v.w);
        }
        const ushort* zp = zq + ((size_t)(b * LSEQ + l0)) * D_INNER + d;
        ushort* yp = yg + ((size_t)(b * LSEQ + l0)) * D_INNER + d;

        for (int l = 0; l < LC; l++) {
            float dtv = b2f(dtp[(size_t)l * D_INNER]);
            float xcv = b2f(xcp[(size_t)l * D_INNER]);
            float zv  = b2f(zp[(size_t)l * D_INNER]);
            float t = dtv * xcv;
            float Bv[16], Cv[16];
            #pragma unroll
            for (int k = 0; k < 4; k++) {
                *(float4*)&Bv[k * 4] = *(const float4*)&sBC[l][k * 4];
                *(float4*)&Cv[k * 4] = *(const float4*)&sBC[l][16 + k * 4];
            }
            float p0 = 0.f, p1 = 0.f, p2 = 0.f, p3 = 0.f;
            #pragma unroll
            for (int n = 0; n < 16; n += 4) {
                float a0 = fexp2(dtv * A[n]);
                float a1 = fexp2(dtv * A[n + 1]);
                float a2 = fexp2(dtv * A[n + 2]);
                float a3 = fexp2(dtv * A[n + 3]);
                h[n]     = h[n] * a0 + t * Bv[n];
                h[n + 1] = h[n + 1] * a1 + t * Bv[n + 1];
                h[n + 2] = h[n + 2] * a2 + t * Bv[n + 2];
                h[n + 3] = h[n + 3] * a3 + t * Bv[n + 3];
                p0 += h[n] * Cv[n];
                p1 += h[n + 1] * Cv[n + 1];
                p2 += h[n + 2] * Cv[n + 2];
                p3 += h[n + 3] * Cv[n + 3];
            }
            float p = (p0 + p1) + (p2 + p3);
            float y = p + Dd * xcv;
            float sz = zv / (1.f + __expf(-zv));
            yp[(size_t)l * D_INNER] = f2b(y * sz);
        }
    }
}

extern "C" void kernel_launch(void* const* d_in, const int* in_sizes, int n_in,
                              void* d_out, int out_size, void* d_ws, size_t ws_size,
                              hipStream_t stream)
{
    const float* hs      = (const float*)d_in[0];
    const float* norm_w  = (const float*)d_in[1];
    const float* inproj  = (const float*)d_in[2];
    const float* convw   = (const float*)d_in[3];
    const float* convb   = (const float*)d_in[4];
    const float* xprojw  = (const float*)d_in[5];
    const float* dtw     = (const float*)d_in[6];
    const float* dtb     = (const float*)d_in[7];
    const float* alog    = (const float*)d_in[8];
    const float* dvec    = (const float*)d_in[9];
    const float* outproj = (const float*)d_in[10];

    float* out_main  = (float*)d_out;
    float* out_resid = (float*)d_out + (size_t)NTOK * D_MODEL;

    char* ws = (char*)d_ws;
    ushort*       xb    = (ushort*)(ws);                     // 384KB boundary rows
    ushort*       zq    = (ushort*)(ws +  8388608);          // 8.4MB
    ushort*       dtq   = (ushort*)(ws + 16777216);          // 8.4MB
    ushort*       xcb   = (ushort*)(ws + 25165824);          // 8.4MB
    unsigned int* ch    = (unsigned int*)(ws + 33554432);    // 16.8MB (bf16 ap,h)
    ushort*       hinit = (ushort*)(ws + 50331648);          // 8.4MB (bf16 h_init)
    float*        xdbl  = (float*) (ws + 67108864);          // 768KB
    ushort*       wIn   = (ushort*)(ws + 67895296);          // 8.4MB
    ushort*       wOut  = (ushort*)(ws + 76283904);          // 4.2MB
    ushort*       h_bf16= (ushort*)(ws + 80478208);          // 4.2MB
    ushort*       xpw_b = (ushort*)(ws + 84672512);          // 384KB
    ushort*       dtw_b = (ushort*)(ws + 85065728);          // 256KB
    ushort*       yg_bf16=(ushort*)(ws + 85327872);          // 8.4MB (end ~93.7MB)

    // K0: prep = rmsnorm + weight cvts + xdbl zero + out zero
    prep_kernel<<<NTOK + 6464 + 192 + 2048, 256, 0, stream>>>(
        hs, norm_w, h_bf16, out_resid,
        inproj, outproj, xprojw, dtw, wIn, wOut, xpw_b, dtw_b, xdbl, out_main);

    // K2: xz GEMM (512 thr, 8 waves) + fused conv/SiLU (x-half) -> xcb, zq, xb
    gemm_xz_kernel<<<dim3(NTOK / 128, (2 * D_INNER) / 128), 512, 0, stream>>>(
        h_bf16, wIn, convw, convb, xcb, xb, zq, D_MODEL);

    // K2b: finish conv for first 3 rows of each 128-token tile
    conv_fixup_kernel<<<48, 256, 0, stream>>>(xb, convw, convb, xcb);

    // K4a: x_dbl GEMM — split-K, 64-row tiles (512 blocks = 2/CU), atomics
    xproj_partial_kernel<<<dim3(NTOK / 64, KSL), 256, 0, stream>>>(
        xcb, xpw_b, xdbl);

    // K4b: dt GEMM (A staged from f32 xdbl) + bias + softplus -> bf16
    dt_gemm_kernel<<<dim3(NTOK / 64, D_INNER / 64), 256, 0, stream>>>(
        xdbl, dtw_b, dtb, dtq);

    // K5: fused scan (A + stitch + C), cooperative — 1024 blocks = 4/CU exact
    {
        void* sargs[] = {(void*)&dtq, (void*)&xcb, (void*)&xdbl, (void*)&zq,
                         (void*)&alog, (void*)&dvec, (void*)&ch, (void*)&hinit,
                         (void*)&yg_bf16};
        hipLaunchCooperativeKernel((const void*)scan_fused_kernel,
                                   dim3(1024), dim3(256), sargs, 0, stream);
    }

    // K6: out = yg @ out_proj_w^T, 64x64 split-K=2 (1024 blocks = 4/CU)
    gemm64_kernel<<<dim3(NTOK / 64, D_MODEL / 64, 2), 256, 0, stream>>>(
        yg_bf16, wOut, out_main, NTOK, D_MODEL, D_INNER);
}

// Round 12
// 259.997 us; speedup vs baseline: 1.8566x; 1.8566x over previous
//
#include <hip/hip_runtime.h>

// ---------- common helpers ----------
typedef __bf16 bf16x8 __attribute__((ext_vector_type(8)));
typedef float f32x4 __attribute__((ext_vector_type(4)));

__device__ __forceinline__ float b2f(ushort u) {
    union { unsigned int i; float f; } v;
    v.i = ((unsigned int)u) << 16;
    return v.f;
}
__device__ __forceinline__ ushort f2b(float f) {
    union { float f; unsigned int i; } v;
    v.f = f;
    unsigned int x = v.i;
    unsigned int r = (x + 0x7fffu + ((x >> 16) & 1u)) >> 16;
    return (ushort)r;
}
__device__ __forceinline__ float fexp2(float x) {
#if __has_builtin(__builtin_amdgcn_exp2f)
    return __builtin_amdgcn_exp2f(x);
#else
    return exp2f(x);
#endif
}
// pack (ap,h) as bf16 pair: lo=ap, hi=h
__device__ __forceinline__ unsigned int packb2(float ap, float h) {
    return ((unsigned int)f2b(h) << 16) | (unsigned int)f2b(ap);
}
// async 16B global->LDS; lane i lands at lds + i*16B (wave-uniform base)
__device__ __forceinline__ void gload16(const ushort* g, ushort* l) {
    __builtin_amdgcn_global_load_lds(
        (const __attribute__((address_space(1))) unsigned int*)g,
        (__attribute__((address_space(3))) unsigned int*)l, 16, 0, 0);
}
// LDS fragment read with XOR chunk swizzle (row stride 64 ushorts, 8 chunks of 8)
__device__ __forceinline__ bf16x8 ldsfrag(const ushort* s, int row, int cq) {
    int p = cq ^ (row & 7);
    return *(const bf16x8*)(s + row * 64 + p * 8);
}

#define D_MODEL 1024
#define D_INNER 2048
#define D_STATE 16
#define DT_RANK 64
#define NTOK    2048   // B*L
#define LSEQ    1024
#define NCH     64     // scan chunks (64: 4 blocks/CU for latency hiding)
#define LC      16     // steps per chunk
#define KSL     16     // xproj K-slices
#define LOG2E   1.44269504088896f

// ---------- K0: prep = RMSNorm + weight cvts + xdbl zero + out zero ----------
__global__ __launch_bounds__(256) void prep_kernel(
    const float* __restrict__ hs, const float* __restrict__ w,
    ushort* __restrict__ hout, float* __restrict__ resid,
    const float* __restrict__ inproj, const float* __restrict__ outproj,
    const float* __restrict__ xprojw, const float* __restrict__ dtw,
    ushort* __restrict__ wIn, ushort* __restrict__ wOut,
    ushort* __restrict__ xpw, ushort* __restrict__ dtwb,
    float* __restrict__ xdbl, float* __restrict__ outz)
{
    int blk = blockIdx.x;
    int tid = threadIdx.x;
    if (blk < NTOK) {
        int t = blk;
        float4 r4 = *(const float4*)(hs + (size_t)t * D_MODEL + tid * 4);
        float s = r4.x * r4.x + r4.y * r4.y + r4.z * r4.z + r4.w * r4.w;
        #pragma unroll
        for (int off = 32; off >= 1; off >>= 1) s += __shfl_xor(s, off);
        __shared__ float red[4];
        int lane = tid & 63, wid = tid >> 6;
        if (lane == 0) red[wid] = s;
        __syncthreads();
        float tot = red[0] + red[1] + red[2] + red[3];
        float inv = 1.0f / (sqrtf(tot) * (1.0f / 32.0f) + 1e-5f);
        float4 w4 = *(const float4*)(w + tid * 4);
        ushort4 o;
        o.x = f2b(w4.x * r4.x * inv);
        o.y = f2b(w4.y * r4.y * inv);
        o.z = f2b(w4.z * r4.z * inv);
        o.w = f2b(w4.w * r4.w * inv);
        *(ushort4*)(hout + (size_t)t * D_MODEL + tid * 4) = o;
        *(float4*)(resid + (size_t)t * D_MODEL + tid * 4) = r4;   // exact copy
    } else if (blk < NTOK + 6464) {
        int i = (blk - NTOK) * 256 + tid;
        const float* src; ushort* dst; int off;
        if (i < 1048576)      { src = inproj;  dst = wIn;  off = i; }
        else if (i < 1572864) { src = outproj; dst = wOut; off = i - 1048576; }
        else if (i < 1622016) { src = xprojw;  dst = xpw;  off = i - 1572864; }
        else if (i < 1654784) { src = dtw;     dst = dtwb; off = i - 1622016; }
        else return;
        float4 v = *(const float4*)(src + (size_t)off * 4);
        ushort4 o;
        o.x = f2b(v.x); o.y = f2b(v.y); o.z = f2b(v.z); o.w = f2b(v.w);
        *(ushort4*)(dst + (size_t)off * 4) = o;
    } else if (blk < NTOK + 6464 + 192) {
        int i = (blk - NTOK - 6464) * 256 + tid;   // 49152 float4s = 196608 floats
        if (i < 49152)
            *(float4*)(xdbl + (size_t)i * 4) = (float4){0.f, 0.f, 0.f, 0.f};
    } else {
        int i = (blk - NTOK - 6464 - 192) * 256 + tid;  // 524288 float4s = out f32
        if (i < 524288)
            *(float4*)(outz + (size_t)i * 4) = (float4){0.f, 0.f, 0.f, 0.f};
    }
}

// ---------- K2: xz GEMM 128x128, 8 waves (512 thr), fused conv/SiLU epilogue ----------
// bn<16: x-half -> conv+SiLU rows 3..127 written to xcb; raw boundary rows
//        {0,1,2,125,126,127} saved to xb for the fixup kernel.
// bn>=16: z-half -> plain bf16 store to zq (LDS-repack coalesced).
// 8 waves/block -> 2 blocks/CU = 4 waves/SIMD: hides barrier drain.
__global__ __launch_bounds__(512) void gemm_xz_kernel(
    const ushort* __restrict__ Ag, const ushort* __restrict__ Wg,
    const float* __restrict__ cw, const float* __restrict__ cb,
    ushort* __restrict__ xcb, ushort* __restrict__ xb,
    ushort* __restrict__ zq, int K)
{
    __shared__ __align__(16) ushort smem[128 * 128];   // 32KB: staging + C repack
    __shared__ float cwl[128][4];
    __shared__ float cbl[128];
    ushort* sA = smem;
    ushort* sB = smem + 128 * 64;
    int tid = threadIdx.x;
    int bm = blockIdx.x, bn = blockIdx.y;
    int wid = tid >> 6, lane = tid & 63;
    int wm = (wid >> 1) * 32, wn = (wid & 1) * 64;   // wave owns 32x64
    int l16 = lane & 15, q = lane >> 4;
    int colbase = (bn & 15) * 128;

    if (bn < 16 && tid < 128) {            // stage conv weights for this col range
        cwl[tid][0] = cw[(size_t)(colbase + tid) * 4 + 0];
        cwl[tid][1] = cw[(size_t)(colbase + tid) * 4 + 1];
        cwl[tid][2] = cw[(size_t)(colbase + tid) * 4 + 2];
        cwl[tid][3] = cw[(size_t)(colbase + tid) * 4 + 3];
        cbl[tid] = cb[colbase + tid];
    }

    f32x4 acc[2][4];
    #pragma unroll
    for (int i = 0; i < 2; i++)
        #pragma unroll
        for (int j = 0; j < 4; j++)
            acc[i][j] = (f32x4){0.f, 0.f, 0.f, 0.f};

    const ushort* Abase = Ag + (size_t)bm * 128 * K;
    const ushort* Wbase = Wg + (size_t)bn * 128 * K;

    int segr = lane >> 3, segc = lane & 7;
    size_t goff[2]; int sseg[2];
    #pragma unroll
    for (int t = 0; t < 2; t++) {          // 16 segs each for A and B, 8 wids x 2
        int s = wid * 2 + t;
        int r = s * 8 + segr;
        int gc = segc ^ (r & 7);
        sseg[t] = s * 512;
        goff[t] = (size_t)r * K + gc * 8;
    }

    for (int k0 = 0; k0 < K; k0 += 64) {
        __syncthreads();
        #pragma unroll
        for (int t = 0; t < 2; t++) {
            gload16(Abase + goff[t] + k0, sA + sseg[t]);
            gload16(Wbase + goff[t] + k0, sB + sseg[t]);
        }
        __syncthreads();
        #pragma unroll
        for (int ks = 0; ks < 2; ks++) {
            int cq = ks * 4 + q;
            bf16x8 af[2], bfr[4];
            #pragma unroll
            for (int i = 0; i < 2; i++)
                af[i] = ldsfrag(sA, wm + i * 16 + l16, cq);
            #pragma unroll
            for (int j = 0; j < 4; j++)
                bfr[j] = ldsfrag(sB, wn + j * 16 + l16, cq);
            #pragma unroll
            for (int i = 0; i < 2; i++)
                #pragma unroll
                for (int j = 0; j < 4; j++)
                    acc[i][j] = __builtin_amdgcn_mfma_f32_16x16x32_bf16(af[i], bfr[j], acc[i][j], 0, 0, 0);
        }
    }

    // repack bf16 C tile into LDS (chunk-XOR vs row to spread banks)
    __syncthreads();
    #pragma unroll
    for (int i = 0; i < 2; i++)
        #pragma unroll
        for (int j = 0; j < 4; j++) {
            int col = wn + j * 16 + l16;
            int cchunk = col >> 3, cin = col & 7;
            #pragma unroll
            for (int r = 0; r < 4; r++) {
                int row = wm + i * 16 + q * 4 + r;
                smem[row * 128 + ((cchunk ^ (row & 7)) << 3) + cin] =
                    f2b(acc[i][j][r]);
            }
        }
    __syncthreads();
    size_t rowbase = (size_t)bm * 128;

    if (bn >= 16) {                        // z-half: plain coalesced store
        int cb2 = (bn - 16) * 128;
        #pragma unroll
        for (int it = 0; it < 4; it++) {
            int flat = it * 4096 + tid * 8;
            int row = flat >> 7, cchunk = (flat & 127) >> 3;
            *(uint4*)(zq + (rowbase + row) * D_INNER + cb2 + (cchunk << 3)) =
                *(const uint4*)(smem + row * 128 + ((cchunk ^ (row & 7)) << 3));
        }
        return;
    }

    // x-half: save raw boundary rows {0,1,2,125,126,127} for the fixup kernel
    if (tid < 96) {
        int rr = tid >> 4;                 // 0..5
        int row = (rr < 3) ? rr : (125 + rr - 3);
        int chunk = tid & 15;
        *(uint4*)(xb + (size_t)(bm * 6 + rr) * D_INNER + colbase + chunk * 8) =
            *(const uint4*)(smem + row * 128 + ((chunk ^ (row & 7)) << 3));
    }

    // fused conv+SiLU for rows 3..127 (l>=3 guaranteed: l=(bm&7)*128+row)
    for (int idx = tid; idx < 2000; idx += 512) {
        int row = (idx >> 4) + 3;
        int chunk = idx & 15;
        ushort tap[4][8];
        #pragma unroll
        for (int k = 0; k < 4; k++) {
            int rk = row - 3 + k;
            *(uint4*)tap[k] =
                *(const uint4*)(smem + rk * 128 + ((chunk ^ (rk & 7)) << 3));
        }
        ushort o[8];
        #pragma unroll
        for (int j = 0; j < 8; j++) {
            int cl = chunk * 8 + j;
            float acc2 = cbl[cl];
            #pragma unroll
            for (int k = 0; k < 4; k++)
                acc2 += b2f(tap[k][j]) * cwl[cl][k];
            o[j] = f2b(acc2 / (1.f + __expf(-acc2)));
        }
        *(uint4*)(xcb + (rowbase + row) * D_INNER + colbase + chunk * 8) =
            *(const uint4*)o;
    }
}

// ---------- K2b: conv fixup for rows 0..2 of each 128-token tile (48 tokens) ----------
__global__ __launch_bounds__(256) void conv_fixup_kernel(
    const ushort* __restrict__ xb, const float* __restrict__ cw,
    const float* __restrict__ cb, ushort* __restrict__ xcb)
{
    int bm = blockIdx.x / 3;               // 0..15
    int r  = blockIdx.x % 3;               // 0..2
    int d0 = threadIdx.x * 8;

    ushort tap[4][8];
    bool has[4];
    #pragma unroll
    for (int k = 0; k < 4; k++) {
        int rt = r - 3 + k;                // token offset within tile, may be <0
        if (rt < 0 && (bm & 7) == 0) {     // l = r here -> causal zero-pad
            has[k] = false;
        } else {
            has[k] = true;
            int bmm, slot;
            if (rt < 0) { bmm = bm - 1; slot = rt + 6; }   // prev rows 125..127 -> 3..5
            else        { bmm = bm;     slot = rt; }       // own rows 0..2
            *(uint4*)tap[k] =
                *(const uint4*)(xb + (size_t)(bmm * 6 + slot) * D_INNER + d0);
        }
    }
    ushort o[8];
    #pragma unroll
    for (int j = 0; j < 8; j++) {
        float4 w4 = *(const float4*)(cw + (size_t)(d0 + j) * 4);
        float wk[4] = {w4.x, w4.y, w4.z, w4.w};
        float acc = cb[d0 + j];
        #pragma unroll
        for (int k = 0; k < 4; k++)
            if (has[k]) acc += b2f(tap[k][j]) * wk[k];
        o[j] = f2b(acc / (1.f + __expf(-acc)));
    }
    *(uint4*)(xcb + (size_t)(bm * 128 + r) * D_INNER + d0) = *(const uint4*)o;
}

// ---------- K6: 64x64 GEMM, split-K=2 (4 blocks/CU), f32 atomic epilogue ----------
__global__ __launch_bounds__(256) void gemm64_kernel(
    const ushort* __restrict__ Ag, const ushort* __restrict__ Wg,
    float* __restrict__ Cf, int M, int N, int K)
{
    __shared__ __align__(16) ushort sA[64 * 64];
    __shared__ __align__(16) ushort sB[64 * 64];
    int tid = threadIdx.x;
    int bm = blockIdx.x, bn = blockIdx.y, bz = blockIdx.z;
    int wid = tid >> 6, lane = tid & 63;
    int wm = wid * 16;
    int l16 = lane & 15, q = lane >> 4;

    f32x4 acc[4];
    #pragma unroll
    for (int j = 0; j < 4; j++) acc[j] = (f32x4){0.f, 0.f, 0.f, 0.f};

    const ushort* Abase = Ag + (size_t)bm * 64 * K;
    const ushort* Wbase = Wg + (size_t)bn * 64 * K;

    int segr = lane >> 3, segc = lane & 7;
    size_t goff[2]; int sseg[2];
    #pragma unroll
    for (int t = 0; t < 2; t++) {
        int s = wid * 2 + t;
        int r = s * 8 + segr;
        int gc = segc ^ (r & 7);
        sseg[t] = s * 512;
        goff[t] = (size_t)r * K + gc * 8;
    }

    int kbeg = bz * (K / 2), kend = kbeg + K / 2;
    for (int k0 = kbeg; k0 < kend; k0 += 64) {
        __syncthreads();
        #pragma unroll
        for (int t = 0; t < 2; t++) {
            gload16(Abase + goff[t] + k0, sA + sseg[t]);
            gload16(Wbase + goff[t] + k0, sB + sseg[t]);
        }
        __syncthreads();
        #pragma unroll
        for (int ks = 0; ks < 2; ks++) {
            int cq = ks * 4 + q;
            bf16x8 af = ldsfrag(sA, wm + l16, cq);
            bf16x8 bfr[4];
            #pragma unroll
            for (int j = 0; j < 4; j++)
                bfr[j] = ldsfrag(sB, j * 16 + l16, cq);
            #pragma unroll
            for (int j = 0; j < 4; j++)
                acc[j] = __builtin_amdgcn_mfma_f32_16x16x32_bf16(af, bfr[j], acc[j], 0, 0, 0);
        }
    }

    int row0 = bm * 64 + wm + q * 4;
    int col0 = bn * 64 + l16;
    #pragma unroll
    for (int j = 0; j < 4; j++)
        #pragma unroll
        for (int r = 0; r < 4; r++)
            atomicAdd(&Cf[(size_t)(row0 + r) * N + col0 + j * 16], acc[j][r]);
}

// ---------- K4a: xproj split-K partial GEMM, 64-row tiles (2 blocks/CU) ----------
// LDS row stride 40 ushorts (80B, 16B-aligned): ~2-way banks vs 8-way at 32
__global__ __launch_bounds__(256) void xproj_partial_kernel(
    const ushort* __restrict__ xcb, const ushort* __restrict__ wq,
    float* __restrict__ xdbl)
{
    __shared__ __align__(16) ushort sA[64 * 40];
    __shared__ __align__(16) ushort sB[96 * 40];
    int tid = threadIdx.x;
    int bm = blockIdx.x, sl = blockIdx.y;    // bm<32 (64-row tiles), sl<16
    int wid = tid >> 6, lane = tid & 63;
    int wm = wid * 16;
    int l16 = lane & 15, q = lane >> 4;

    f32x4 acc[6];
    #pragma unroll
    for (int j = 0; j < 6; j++)
        acc[j] = (f32x4){0.f, 0.f, 0.f, 0.f};

    const ushort* Abase = xcb + (size_t)bm * 64 * D_INNER;
    int kbase = sl * (D_INNER / KSL);

    for (int kk = 0; kk < D_INNER / KSL; kk += 32) {
        int k0 = kbase + kk;
        __syncthreads();
        {
            int r = tid >> 2, c = (tid & 3) << 3;   // 256 uint4 = 64 rows x 32 cols
            *(uint4*)(sA + r * 40 + c) = *(const uint4*)(Abase + (size_t)r * D_INNER + k0 + c);
        }
        for (int i = tid; i < 384; i += 256) {
            int r = i >> 2, c = (i & 3) << 3;
            *(uint4*)(sB + r * 40 + c) = *(const uint4*)(wq + (size_t)r * D_INNER + k0 + c);
        }
        __syncthreads();
        bf16x8 af = *(const bf16x8*)(sA + (wm + l16) * 40 + q * 8);
        bf16x8 bfr[6];
        #pragma unroll
        for (int j = 0; j < 6; j++)
            bfr[j] = *(const bf16x8*)(sB + (j * 16 + l16) * 40 + q * 8);
        #pragma unroll
        for (int j = 0; j < 6; j++)
            acc[j] = __builtin_amdgcn_mfma_f32_16x16x32_bf16(af, bfr[j], acc[j], 0, 0, 0);
    }

    int row0 = bm * 64 + wm + q * 4;
    #pragma unroll
    for (int j = 0; j < 6; j++)
        #pragma unroll
        for (int r = 0; r < 4; r++)
            atomicAdd(&xdbl[(size_t)(row0 + r) * 96 + j * 16 + l16], acc[j][r]);
}

// ---------- K4b: dt = softplus(xdbl[:, :64] @ dt_proj_w^T + b) -> bf16 ----------
__global__ __launch_bounds__(256) void dt_gemm_kernel(
    const float* __restrict__ xdbl, const ushort* __restrict__ dtwq,
    const float* __restrict__ dtb, ushort* __restrict__ dtout)
{
    __shared__ __align__(16) ushort sA[64 * 72];
    __shared__ __align__(16) ushort sB[64 * 72];
    int tid = threadIdx.x;
    int bm = blockIdx.x, bn = blockIdx.y;
    int wid = tid >> 6, lane = tid & 63;
    int wm = wid * 16;
    int l16 = lane & 15, q = lane >> 4;

    const float* Abase = xdbl + (size_t)bm * 64 * 96;
    const ushort* Bbase = dtwq + (size_t)bn * 64 * DT_RANK;
    #pragma unroll
    for (int i = tid; i < 512; i += 256) {
        int r = i >> 3, c = (i & 7) << 3;
        float4 v0 = *(const float4*)(Abase + (size_t)r * 96 + c);
        float4 v1 = *(const float4*)(Abase + (size_t)r * 96 + c + 4);
        ushort o[8] = {f2b(v0.x), f2b(v0.y), f2b(v0.z), f2b(v0.w),
                       f2b(v1.x), f2b(v1.y), f2b(v1.z), f2b(v1.w)};
        *(uint4*)(sA + r * 72 + c) = *(const uint4*)o;
        *(uint4*)(sB + r * 72 + c) = *(const uint4*)(Bbase + (size_t)r * DT_RANK + c);
    }
    __syncthreads();

    f32x4 acc[4];
    #pragma unroll
    for (int j = 0; j < 4; j++) acc[j] = (f32x4){0.f, 0.f, 0.f, 0.f};

    #pragma unroll
    for (int ks = 0; ks < 2; ks++) {
        bf16x8 af = *(const bf16x8*)(sA + (wm + l16) * 72 + ks * 32 + q * 8);
        bf16x8 bfr[4];
        #pragma unroll
        for (int j = 0; j < 4; j++)
            bfr[j] = *(const bf16x8*)(sB + (j * 16 + l16) * 72 + ks * 32 + q * 8);
        #pragma unroll
        for (int j = 0; j < 4; j++)
            acc[j] = __builtin_amdgcn_mfma_f32_16x16x32_bf16(af, bfr[j], acc[j], 0, 0, 0);
    }

    __syncthreads();
    #pragma unroll
    for (int j = 0; j < 4; j++) {
        float bias = dtb[bn * 64 + j * 16 + l16];
        #pragma unroll
        for (int r = 0; r < 4; r++) {
            float s = acc[j][r] + bias;
            float sp = (s > 20.f) ? s : log1pf(__expf(s));
            sA[(wm + q * 4 + r) * 72 + j * 16 + l16] = f2b(sp);
        }
    }
    __syncthreads();
    int row0 = bm * 64, col0 = bn * 64;
    #pragma unroll
    for (int rep = 0; rep < 2; rep++) {
        int off = rep * 2048 + tid * 8;
        int row = off >> 6, col = off & 63;
        *(uint4*)(dtout + (size_t)(row0 + row) * D_INNER + col0 + col) =
            *(const uint4*)(sA + row * 72 + col);
    }
}

// ---------- K5a: scan pass A — lane-owns-d, NCH=64, bf16-packed (ap,h) ----------
__global__ __launch_bounds__(256) void scan_partA_kernel(
    const ushort* __restrict__ dt, const ushort* __restrict__ xcq,
    const float* __restrict__ xdbl, const float* __restrict__ Alog,
    unsigned int* __restrict__ ch)
{
    __shared__ float sBC[LC][32];
    int bid = blockIdx.x;                  // 1024 = b(2) x chunk(64) x dgroup(8)
    int g = bid & 7;
    int c = (bid >> 3) & (NCH - 1);
    int b = bid >> 9;
    int tid = threadIdx.x;
    int lane = tid & 63, wid = tid >> 6;
    int d = g * 256 + wid * 64 + lane;
    int l0 = c * LC;

    if (tid < LC * 8) {                    // stage B/C tile (16 rows x 32 floats)
        int r = tid >> 3, c4 = (tid & 7) * 4;
        *(float4*)&sBC[r][c4] =
            *(const float4*)(xdbl + ((size_t)(b * LSEQ + l0 + r)) * 96 + 64 + c4);
    }
    float A[16];
    #pragma unroll
    for (int k = 0; k < 4; k++)
        *(float4*)&A[k * 4] = *(const float4*)(Alog + d * D_STATE + k * 4);
    #pragma unroll
    for (int n = 0; n < 16; n++) A[n] = -__expf(A[n]) * LOG2E;
    __syncthreads();

    const ushort* dtp = dt  + ((size_t)(b * LSEQ + l0)) * D_INNER + d;
    const ushort* xcp = xcq + ((size_t)(b * LSEQ + l0)) * D_INNER + d;

    float h[16];
    #pragma unroll
    for (int n = 0; n < 16; n++) h[n] = 0.f;
    float S = 0.f;                         // sum of dtv; prod a = exp2(A*S)

    for (int l = 0; l < LC; l++) {
        float dtv = b2f(dtp[(size_t)l * D_INNER]);
        float xcv = b2f(xcp[(size_t)l * D_INNER]);
        float t = dtv * xcv;
        S += dtv;
        float Bv[16];
        #pragma unroll
        for (int k = 0; k < 4; k++)
            *(float4*)&Bv[k * 4] = *(const float4*)&sBC[l][k * 4];
        #pragma unroll
        for (int n = 0; n < 16; n++) {
            float a = fexp2(dtv * A[n]);
            h[n] = h[n] * a + t * Bv[n];
        }
    }

    unsigned int* outp = ch + (((size_t)(c * 2 + b)) << 15) + (d << 4);
    #pragma unroll
    for (int n = 0; n < 16; n += 4) {
        uint4 v;
        v.x = packb2(fexp2(A[n] * S),     h[n]);
        v.y = packb2(fexp2(A[n + 1] * S), h[n + 1]);
        v.z = packb2(fexp2(A[n + 2] * S), h[n + 2]);
        v.w = packb2(fexp2(A[n + 3] * S), h[n + 3]);
        *(uint4*)&outp[n] = v;
    }
}

// ---------- K5c: scan pass C with in-block lookback (replaces stitch kernel) ----------
// Each block folds ch[0..c-1] for its own (b,d) to get h_init in f32 (load
// addresses are data-independent -> pipelined; dependence chain is VALU-only),
// then runs the fused C-proj + D-skip + gate scan. No cross-block ordering.
__global__ __launch_bounds__(256) void scan_partC_kernel(
    const ushort* __restrict__ dt, const ushort* __restrict__ xcq,
    const float* __restrict__ xdbl, const ushort* __restrict__ zq,
    const float* __restrict__ Alog, const float* __restrict__ Dp,
    const unsigned int* __restrict__ ch, ushort* __restrict__ yg)
{
    __shared__ float sBC[LC][32];
    int bid = blockIdx.x;
    int g = bid & 7;
    int c = (bid >> 3) & (NCH - 1);
    int b = bid >> 9;
    int tid = threadIdx.x;
    int lane = tid & 63, wid = tid >> 6;
    int d = g * 256 + wid * 64 + lane;
    int l0 = c * LC;

    if (tid < LC * 8) {
        int r = tid >> 3, c4 = (tid & 7) * 4;
        *(float4*)&sBC[r][c4] =
            *(const float4*)(xdbl + ((size_t)(b * LSEQ + l0 + r)) * 96 + 64 + c4);
    }
    float A[16];
    #pragma unroll
    for (int k = 0; k < 4; k++)
        *(float4*)&A[k * 4] = *(const float4*)(Alog + d * D_STATE + k * 4);
    #pragma unroll
    for (int n = 0; n < 16; n++) A[n] = -__expf(A[n]) * LOG2E;
    float Dd = Dp[d];

    // lookback: h_init = fold over chunks 0..c-1 (f32 accum, no bf16 round-trip)
    float h[16];
    #pragma unroll
    for (int n = 0; n < 16; n++) h[n] = 0.f;
    {
        const unsigned int* chd = ch + (d << 4);
        for (int c2 = 0; c2 < c; c2++) {
            const uint4* p = (const uint4*)(chd + (((size_t)(c2 * 2 + b)) << 15));
            uint4 v0 = p[0], v1 = p[1], v2 = p[2], v3 = p[3];
            unsigned int vv[16] = {v0.x, v0.y, v0.z, v0.w,
                                   v1.x, v1.y, v1.z, v1.w,
                                   v2.x, v2.y, v2.z, v2.w,
                                   v3.x, v3.y, v3.z, v3.w};
            #pragma unroll
            for (int n = 0; n < 16; n++) {
                float ap = b2f((ushort)(vv[n] & 0xffffu));
                float hh = b2f((ushort)(vv[n] >> 16));
                h[n] = ap * h[n] + hh;
            }
        }
    }
    __syncthreads();

    const ushort* dtp = dt  + ((size_t)(b * LSEQ + l0)) * D_INNER + d;
    const ushort* xcp = xcq + ((size_t)(b * LSEQ + l0)) * D_INNER + d;
    const ushort* zp  = zq  + ((size_t)(b * LSEQ + l0)) * D_INNER + d;
    ushort* yp = yg + ((size_t)(b * LSEQ + l0)) * D_INNER + d;

    for (int l = 0; l < LC; l++) {
        float dtv = b2f(dtp[(size_t)l * D_INNER]);
        float xcv = b2f(xcp[(size_t)l * D_INNER]);
        float zv  = b2f(zp[(size_t)l * D_INNER]);
        float t = dtv * xcv;
        float Bv[16], Cv[16];
        #pragma unroll
        for (int k = 0; k < 4; k++) {
            *(float4*)&Bv[k * 4] = *(const float4*)&sBC[l][k * 4];
            *(float4*)&Cv[k * 4] = *(const float4*)&sBC[l][16 + k * 4];
        }
        float p0 = 0.f, p1 = 0.f, p2 = 0.f, p3 = 0.f;
        #pragma unroll
        for (int n = 0; n < 16; n += 4) {
            float a0 = fexp2(dtv * A[n]);
            float a1 = fexp2(dtv * A[n + 1]);
            float a2 = fexp2(dtv * A[n + 2]);
            float a3 = fexp2(dtv * A[n + 3]);
            h[n]     = h[n] * a0 + t * Bv[n];
            h[n + 1] = h[n + 1] * a1 + t * Bv[n + 1];
            h[n + 2] = h[n + 2] * a2 + t * Bv[n + 2];
            h[n + 3] = h[n + 3] * a3 + t * Bv[n + 3];
            p0 += h[n] * Cv[n];
            p1 += h[n + 1] * Cv[n + 1];
            p2 += h[n + 2] * Cv[n + 2];
            p3 += h[n + 3] * Cv[n + 3];
        }
        float p = (p0 + p1) + (p2 + p3);
        float y = p + Dd * xcv;
        float sz = zv / (1.f + __expf(-zv));
        yp[(size_t)l * D_INNER] = f2b(y * sz);
    }
}

extern "C" void kernel_launch(void* const* d_in, const int* in_sizes, int n_in,
                              void* d_out, int out_size, void* d_ws, size_t ws_size,
                              hipStream_t stream)
{
    const float* hs      = (const float*)d_in[0];
    const float* norm_w  = (const float*)d_in[1];
    const float* inproj  = (const float*)d_in[2];
    const float* convw   = (const float*)d_in[3];
    const float* convb   = (const float*)d_in[4];
    const float* xprojw  = (const float*)d_in[5];
    const float* dtw     = (const float*)d_in[6];
    const float* dtb     = (const float*)d_in[7];
    const float* alog    = (const float*)d_in[8];
    const float* dvec    = (const float*)d_in[9];
    const float* outproj = (const float*)d_in[10];

    float* out_main  = (float*)d_out;
    float* out_resid = (float*)d_out + (size_t)NTOK * D_MODEL;

    char* ws = (char*)d_ws;
    ushort*       xb    = (ushort*)(ws);                     // 384KB boundary rows
    ushort*       zq    = (ushort*)(ws +  8388608);          // 8.4MB
    ushort*       dtq   = (ushort*)(ws + 16777216);          // 8.4MB
    ushort*       xcb   = (ushort*)(ws + 25165824);          // 8.4MB
    unsigned int* ch    = (unsigned int*)(ws + 33554432);    // 16.8MB (bf16 ap,h)
    float*        xdbl  = (float*) (ws + 67108864);          // 768KB
    ushort*       wIn   = (ushort*)(ws + 67895296);          // 8.4MB
    ushort*       wOut  = (ushort*)(ws + 76283904);          // 4.2MB
    ushort*       h_bf16= (ushort*)(ws + 80478208);          // 4.2MB
    ushort*       xpw_b = (ushort*)(ws + 84672512);          // 384KB
    ushort*       dtw_b = (ushort*)(ws + 85065728);          // 256KB
    ushort*       yg_bf16=(ushort*)(ws + 85327872);          // 8.4MB (end ~93.7MB)

    // K0: prep = rmsnorm + weight cvts + xdbl zero + out zero
    prep_kernel<<<NTOK + 6464 + 192 + 2048, 256, 0, stream>>>(
        hs, norm_w, h_bf16, out_resid,
        inproj, outproj, xprojw, dtw, wIn, wOut, xpw_b, dtw_b, xdbl, out_main);

    // K2: xz GEMM (512 thr, 8 waves) + fused conv/SiLU (x-half) -> xcb, zq, xb
    gemm_xz_kernel<<<dim3(NTOK / 128, (2 * D_INNER) / 128), 512, 0, stream>>>(
        h_bf16, wIn, convw, convb, xcb, xb, zq, D_MODEL);

    // K2b: finish conv for first 3 rows of each 128-token tile
    conv_fixup_kernel<<<48, 256, 0, stream>>>(xb, convw, convb, xcb);

    // K4a: x_dbl GEMM — split-K, 64-row tiles (512 blocks = 2/CU), atomics
    xproj_partial_kernel<<<dim3(NTOK / 64, KSL), 256, 0, stream>>>(
        xcb, xpw_b, xdbl);

    // K4b: dt GEMM (A staged from f32 xdbl) + bias + softplus -> bf16
    dt_gemm_kernel<<<dim3(NTOK / 64, D_INNER / 64), 256, 0, stream>>>(
        xdbl, dtw_b, dtb, dtq);

    // K5: chunked parallel scan — part A, then part C with in-block lookback
    scan_partA_kernel<<<1024, 256, 0, stream>>>(dtq, xcb, xdbl, alog, ch);
    scan_partC_kernel<<<1024, 256, 0, stream>>>(dtq, xcb, xdbl, zq,
                                                alog, dvec, ch, yg_bf16);

    // K6: out = yg @ out_proj_w^T, 64x64 split-K=2 (1024 blocks = 4/CU)
    gemm64_kernel<<<dim3(NTOK / 64, D_MODEL / 64, 2), 256, 0, stream>>>(
        yg_bf16, wOut, out_main, NTOK, D_MODEL, D_INNER);
}

// Round 13
// 235.587 us; speedup vs baseline: 2.0490x; 1.1036x over previous
//
#include <hip/hip_runtime.h>

// ---------- common helpers ----------
typedef __bf16 bf16x8 __attribute__((ext_vector_type(8)));
typedef float f32x4 __attribute__((ext_vector_type(4)));

__device__ __forceinline__ float b2f(ushort u) {
    union { unsigned int i; float f; } v;
    v.i = ((unsigned int)u) << 16;
    return v.f;
}
__device__ __forceinline__ ushort f2b(float f) {
    union { float f; unsigned int i; } v;
    v.f = f;
    unsigned int x = v.i;
    unsigned int r = (x + 0x7fffu + ((x >> 16) & 1u)) >> 16;
    return (ushort)r;
}
__device__ __forceinline__ float fexp2(float x) {
#if __has_builtin(__builtin_amdgcn_exp2f)
    return __builtin_amdgcn_exp2f(x);
#else
    return exp2f(x);
#endif
}
// pack (ap,h) as bf16 pair: lo=ap, hi=h
__device__ __forceinline__ unsigned int packb2(float ap, float h) {
    return ((unsigned int)f2b(h) << 16) | (unsigned int)f2b(ap);
}
// -exp(v)*log2e per component (SSA float4, never address-taken)
__device__ __forceinline__ float4 negexp4(float4 v) {
    v.x = -__expf(v.x) * 1.44269504088896f;
    v.y = -__expf(v.y) * 1.44269504088896f;
    v.z = -__expf(v.z) * 1.44269504088896f;
    v.w = -__expf(v.w) * 1.44269504088896f;
    return v;
}
// async 16B global->LDS; lane i lands at lds + i*16B (wave-uniform base)
__device__ __forceinline__ void gload16(const ushort* g, ushort* l) {
    __builtin_amdgcn_global_load_lds(
        (const __attribute__((address_space(1))) unsigned int*)g,
        (__attribute__((address_space(3))) unsigned int*)l, 16, 0, 0);
}
// LDS fragment read with XOR chunk swizzle (row stride 64 ushorts, 8 chunks of 8)
__device__ __forceinline__ bf16x8 ldsfrag(const ushort* s, int row, int cq) {
    int p = cq ^ (row & 7);
    return *(const bf16x8*)(s + row * 64 + p * 8);
}

#define D_MODEL 1024
#define D_INNER 2048
#define D_STATE 16
#define DT_RANK 64
#define NTOK    2048   // B*L
#define LSEQ    1024
#define NCH     64     // scan chunks (64: 4 blocks/CU for latency hiding)
#define LC      16     // steps per chunk
#define KSL     16     // xproj K-slices
#define LOG2E   1.44269504088896f

// scan step on one float4 group, all named SSA (no scratch)
#define SSTEP(hv, Av, Bv) \
    hv.x = hv.x * fexp2(dtv * Av.x) + t * Bv.x; \
    hv.y = hv.y * fexp2(dtv * Av.y) + t * Bv.y; \
    hv.z = hv.z * fexp2(dtv * Av.z) + t * Bv.z; \
    hv.w = hv.w * fexp2(dtv * Av.w) + t * Bv.w;

#define CSTEP(hv, Av, Bv, Cv) \
    hv.x = hv.x * fexp2(dtv * Av.x) + t * Bv.x; p0 += hv.x * Cv.x; \
    hv.y = hv.y * fexp2(dtv * Av.y) + t * Bv.y; p1 += hv.y * Cv.y; \
    hv.z = hv.z * fexp2(dtv * Av.z) + t * Bv.z; p2 += hv.z * Cv.z; \
    hv.w = hv.w * fexp2(dtv * Av.w) + t * Bv.w; p3 += hv.w * Cv.w;

// ---------- K0: prep = RMSNorm + weight cvts + xdbl zero + out zero ----------
__global__ __launch_bounds__(256) void prep_kernel(
    const float* __restrict__ hs, const float* __restrict__ w,
    ushort* __restrict__ hout, float* __restrict__ resid,
    const float* __restrict__ inproj, const float* __restrict__ outproj,
    const float* __restrict__ xprojw, const float* __restrict__ dtw,
    ushort* __restrict__ wIn, ushort* __restrict__ wOut,
    ushort* __restrict__ xpw, ushort* __restrict__ dtwb,
    float* __restrict__ xdbl, float* __restrict__ outz)
{
    int blk = blockIdx.x;
    int tid = threadIdx.x;
    if (blk < NTOK) {
        int t = blk;
        float4 r4 = *(const float4*)(hs + (size_t)t * D_MODEL + tid * 4);
        float s = r4.x * r4.x + r4.y * r4.y + r4.z * r4.z + r4.w * r4.w;
        #pragma unroll
        for (int off = 32; off >= 1; off >>= 1) s += __shfl_xor(s, off);
        __shared__ float red[4];
        int lane = tid & 63, wid = tid >> 6;
        if (lane == 0) red[wid] = s;
        __syncthreads();
        float tot = red[0] + red[1] + red[2] + red[3];
        float inv = 1.0f / (sqrtf(tot) * (1.0f / 32.0f) + 1e-5f);
        float4 w4 = *(const float4*)(w + tid * 4);
        ushort4 o;
        o.x = f2b(w4.x * r4.x * inv);
        o.y = f2b(w4.y * r4.y * inv);
        o.z = f2b(w4.z * r4.z * inv);
        o.w = f2b(w4.w * r4.w * inv);
        *(ushort4*)(hout + (size_t)t * D_MODEL + tid * 4) = o;
        *(float4*)(resid + (size_t)t * D_MODEL + tid * 4) = r4;   // exact copy
    } else if (blk < NTOK + 6464) {
        int i = (blk - NTOK) * 256 + tid;
        const float* src; ushort* dst; int off;
        if (i < 1048576)      { src = inproj;  dst = wIn;  off = i; }
        else if (i < 1572864) { src = outproj; dst = wOut; off = i - 1048576; }
        else if (i < 1622016) { src = xprojw;  dst = xpw;  off = i - 1572864; }
        else if (i < 1654784) { src = dtw;     dst = dtwb; off = i - 1622016; }
        else return;
        float4 v = *(const float4*)(src + (size_t)off * 4);
        ushort4 o;
        o.x = f2b(v.x); o.y = f2b(v.y); o.z = f2b(v.z); o.w = f2b(v.w);
        *(ushort4*)(dst + (size_t)off * 4) = o;
    } else if (blk < NTOK + 6464 + 192) {
        int i = (blk - NTOK - 6464) * 256 + tid;   // 49152 float4s = 196608 floats
        if (i < 49152)
            *(float4*)(xdbl + (size_t)i * 4) = (float4){0.f, 0.f, 0.f, 0.f};
    } else {
        int i = (blk - NTOK - 6464 - 192) * 256 + tid;  // 524288 float4s = out f32
        if (i < 524288)
            *(float4*)(outz + (size_t)i * 4) = (float4){0.f, 0.f, 0.f, 0.f};
    }
}

// ---------- K2: xz GEMM 128x128, 8 waves (512 thr), fused conv/SiLU epilogue ----------
__global__ __launch_bounds__(512) void gemm_xz_kernel(
    const ushort* __restrict__ Ag, const ushort* __restrict__ Wg,
    const float* __restrict__ cw, const float* __restrict__ cb,
    ushort* __restrict__ xcb, ushort* __restrict__ xb,
    ushort* __restrict__ zq, int K)
{
    __shared__ __align__(16) ushort smem[128 * 128];   // 32KB: staging + C repack
    __shared__ float cwl[128][4];
    __shared__ float cbl[128];
    ushort* sA = smem;
    ushort* sB = smem + 128 * 64;
    int tid = threadIdx.x;
    int bm = blockIdx.x, bn = blockIdx.y;
    int wid = tid >> 6, lane = tid & 63;
    int wm = (wid >> 1) * 32, wn = (wid & 1) * 64;   // wave owns 32x64
    int l16 = lane & 15, q = lane >> 4;
    int colbase = (bn & 15) * 128;

    if (bn < 16 && tid < 128) {            // stage conv weights for this col range
        cwl[tid][0] = cw[(size_t)(colbase + tid) * 4 + 0];
        cwl[tid][1] = cw[(size_t)(colbase + tid) * 4 + 1];
        cwl[tid][2] = cw[(size_t)(colbase + tid) * 4 + 2];
        cwl[tid][3] = cw[(size_t)(colbase + tid) * 4 + 3];
        cbl[tid] = cb[colbase + tid];
    }

    f32x4 acc[2][4];
    #pragma unroll
    for (int i = 0; i < 2; i++)
        #pragma unroll
        for (int j = 0; j < 4; j++)
            acc[i][j] = (f32x4){0.f, 0.f, 0.f, 0.f};

    const ushort* Abase = Ag + (size_t)bm * 128 * K;
    const ushort* Wbase = Wg + (size_t)bn * 128 * K;

    int segr = lane >> 3, segc = lane & 7;
    size_t goff[2]; int sseg[2];
    #pragma unroll
    for (int t = 0; t < 2; t++) {          // 16 segs each for A and B, 8 wids x 2
        int s = wid * 2 + t;
        int r = s * 8 + segr;
        int gc = segc ^ (r & 7);
        sseg[t] = s * 512;
        goff[t] = (size_t)r * K + gc * 8;
    }

    for (int k0 = 0; k0 < K; k0 += 64) {
        __syncthreads();
        #pragma unroll
        for (int t = 0; t < 2; t++) {
            gload16(Abase + goff[t] + k0, sA + sseg[t]);
            gload16(Wbase + goff[t] + k0, sB + sseg[t]);
        }
        __syncthreads();
        #pragma unroll
        for (int ks = 0; ks < 2; ks++) {
            int cq = ks * 4 + q;
            bf16x8 af[2], bfr[4];
            #pragma unroll
            for (int i = 0; i < 2; i++)
                af[i] = ldsfrag(sA, wm + i * 16 + l16, cq);
            #pragma unroll
            for (int j = 0; j < 4; j++)
                bfr[j] = ldsfrag(sB, wn + j * 16 + l16, cq);
            #pragma unroll
            for (int i = 0; i < 2; i++)
                #pragma unroll
                for (int j = 0; j < 4; j++)
                    acc[i][j] = __builtin_amdgcn_mfma_f32_16x16x32_bf16(af[i], bfr[j], acc[i][j], 0, 0, 0);
        }
    }

    // repack bf16 C tile into LDS (chunk-XOR vs row to spread banks)
    __syncthreads();
    #pragma unroll
    for (int i = 0; i < 2; i++)
        #pragma unroll
        for (int j = 0; j < 4; j++) {
            int col = wn + j * 16 + l16;
            int cchunk = col >> 3, cin = col & 7;
            #pragma unroll
            for (int r = 0; r < 4; r++) {
                int row = wm + i * 16 + q * 4 + r;
                smem[row * 128 + ((cchunk ^ (row & 7)) << 3) + cin] =
                    f2b(acc[i][j][r]);
            }
        }
    __syncthreads();
    size_t rowbase = (size_t)bm * 128;

    if (bn >= 16) {                        // z-half: plain coalesced store
        int cb2 = (bn - 16) * 128;
        #pragma unroll
        for (int it = 0; it < 4; it++) {
            int flat = it * 4096 + tid * 8;
            int row = flat >> 7, cchunk = (flat & 127) >> 3;
            *(uint4*)(zq + (rowbase + row) * D_INNER + cb2 + (cchunk << 3)) =
                *(const uint4*)(smem + row * 128 + ((cchunk ^ (row & 7)) << 3));
        }
        return;
    }

    // x-half: save raw boundary rows {0,1,2,125,126,127} for the fixup kernel
    if (tid < 96) {
        int rr = tid >> 4;                 // 0..5
        int row = (rr < 3) ? rr : (125 + rr - 3);
        int chunk = tid & 15;
        *(uint4*)(xb + (size_t)(bm * 6 + rr) * D_INNER + colbase + chunk * 8) =
            *(const uint4*)(smem + row * 128 + ((chunk ^ (row & 7)) << 3));
    }

    // fused conv+SiLU for rows 3..127 (l>=3 guaranteed: l=(bm&7)*128+row)
    for (int idx = tid; idx < 2000; idx += 512) {
        int row = (idx >> 4) + 3;
        int chunk = idx & 15;
        ushort tap[4][8];
        #pragma unroll
        for (int k = 0; k < 4; k++) {
            int rk = row - 3 + k;
            *(uint4*)tap[k] =
                *(const uint4*)(smem + rk * 128 + ((chunk ^ (rk & 7)) << 3));
        }
        ushort o[8];
        #pragma unroll
        for (int j = 0; j < 8; j++) {
            int cl = chunk * 8 + j;
            float acc2 = cbl[cl];
            #pragma unroll
            for (int k = 0; k < 4; k++)
                acc2 += b2f(tap[k][j]) * cwl[cl][k];
            o[j] = f2b(acc2 / (1.f + __expf(-acc2)));
        }
        *(uint4*)(xcb + (rowbase + row) * D_INNER + colbase + chunk * 8) =
            *(const uint4*)o;
    }
}

// ---------- K2b: conv fixup for rows 0..2 of each 128-token tile (48 tokens) ----------
__global__ __launch_bounds__(256) void conv_fixup_kernel(
    const ushort* __restrict__ xb, const float* __restrict__ cw,
    const float* __restrict__ cb, ushort* __restrict__ xcb)
{
    int bm = blockIdx.x / 3;               // 0..15
    int r  = blockIdx.x % 3;               // 0..2
    int d0 = threadIdx.x * 8;

    ushort tap[4][8];
    bool has[4];
    #pragma unroll
    for (int k = 0; k < 4; k++) {
        int rt = r - 3 + k;                // token offset within tile, may be <0
        if (rt < 0 && (bm & 7) == 0) {     // l = r here -> causal zero-pad
            has[k] = false;
        } else {
            has[k] = true;
            int bmm, slot;
            if (rt < 0) { bmm = bm - 1; slot = rt + 6; }   // prev rows 125..127 -> 3..5
            else        { bmm = bm;     slot = rt; }       // own rows 0..2
            *(uint4*)tap[k] =
                *(const uint4*)(xb + (size_t)(bmm * 6 + slot) * D_INNER + d0);
        }
    }
    ushort o[8];
    #pragma unroll
    for (int j = 0; j < 8; j++) {
        float4 w4 = *(const float4*)(cw + (size_t)(d0 + j) * 4);
        float wk[4] = {w4.x, w4.y, w4.z, w4.w};
        float acc = cb[d0 + j];
        #pragma unroll
        for (int k = 0; k < 4; k++)
            if (has[k]) acc += b2f(tap[k][j]) * wk[k];
        o[j] = f2b(acc / (1.f + __expf(-acc)));
    }
    *(uint4*)(xcb + (size_t)(bm * 128 + r) * D_INNER + d0) = *(const uint4*)o;
}

// ---------- K6: 64x64 GEMM, split-K=2 (4 blocks/CU), f32 atomic epilogue ----------
__global__ __launch_bounds__(256) void gemm64_kernel(
    const ushort* __restrict__ Ag, const ushort* __restrict__ Wg,
    float* __restrict__ Cf, int M, int N, int K)
{
    __shared__ __align__(16) ushort sA[64 * 64];
    __shared__ __align__(16) ushort sB[64 * 64];
    int tid = threadIdx.x;
    int bm = blockIdx.x, bn = blockIdx.y, bz = blockIdx.z;
    int wid = tid >> 6, lane = tid & 63;
    int wm = wid * 16;
    int l16 = lane & 15, q = lane >> 4;

    f32x4 acc[4];
    #pragma unroll
    for (int j = 0; j < 4; j++) acc[j] = (f32x4){0.f, 0.f, 0.f, 0.f};

    const ushort* Abase = Ag + (size_t)bm * 64 * K;
    const ushort* Wbase = Wg + (size_t)bn * 64 * K;

    int segr = lane >> 3, segc = lane & 7;
    size_t goff[2]; int sseg[2];
    #pragma unroll
    for (int t = 0; t < 2; t++) {
        int s = wid * 2 + t;
        int r = s * 8 + segr;
        int gc = segc ^ (r & 7);
        sseg[t] = s * 512;
        goff[t] = (size_t)r * K + gc * 8;
    }

    int kbeg = bz * (K / 2), kend = kbeg + K / 2;
    for (int k0 = kbeg; k0 < kend; k0 += 64) {
        __syncthreads();
        #pragma unroll
        for (int t = 0; t < 2; t++) {
            gload16(Abase + goff[t] + k0, sA + sseg[t]);
            gload16(Wbase + goff[t] + k0, sB + sseg[t]);
        }
        __syncthreads();
        #pragma unroll
        for (int ks = 0; ks < 2; ks++) {
            int cq = ks * 4 + q;
            bf16x8 af = ldsfrag(sA, wm + l16, cq);
            bf16x8 bfr[4];
            #pragma unroll
            for (int j = 0; j < 4; j++)
                bfr[j] = ldsfrag(sB, j * 16 + l16, cq);
            #pragma unroll
            for (int j = 0; j < 4; j++)
                acc[j] = __builtin_amdgcn_mfma_f32_16x16x32_bf16(af, bfr[j], acc[j], 0, 0, 0);
        }
    }

    int row0 = bm * 64 + wm + q * 4;
    int col0 = bn * 64 + l16;
    #pragma unroll
    for (int j = 0; j < 4; j++)
        #pragma unroll
        for (int r = 0; r < 4; r++)
            atomicAdd(&Cf[(size_t)(row0 + r) * N + col0 + j * 16], acc[j][r]);
}

// ---------- K4a: xproj split-K partial GEMM, 64-row tiles (2 blocks/CU) ----------
__global__ __launch_bounds__(256) void xproj_partial_kernel(
    const ushort* __restrict__ xcb, const ushort* __restrict__ wq,
    float* __restrict__ xdbl)
{
    __shared__ __align__(16) ushort sA[64 * 40];
    __shared__ __align__(16) ushort sB[96 * 40];
    int tid = threadIdx.x;
    int bm = blockIdx.x, sl = blockIdx.y;    // bm<32 (64-row tiles), sl<16
    int wid = tid >> 6, lane = tid & 63;
    int wm = wid * 16;
    int l16 = lane & 15, q = lane >> 4;

    f32x4 acc[6];
    #pragma unroll
    for (int j = 0; j < 6; j++)
        acc[j] = (f32x4){0.f, 0.f, 0.f, 0.f};

    const ushort* Abase = xcb + (size_t)bm * 64 * D_INNER;
    int kbase = sl * (D_INNER / KSL);

    for (int kk = 0; kk < D_INNER / KSL; kk += 32) {
        int k0 = kbase + kk;
        __syncthreads();
        {
            int r = tid >> 2, c = (tid & 3) << 3;   // 256 uint4 = 64 rows x 32 cols
            *(uint4*)(sA + r * 40 + c) = *(const uint4*)(Abase + (size_t)r * D_INNER + k0 + c);
        }
        for (int i = tid; i < 384; i += 256) {
            int r = i >> 2, c = (i & 3) << 3;
            *(uint4*)(sB + r * 40 + c) = *(const uint4*)(wq + (size_t)r * D_INNER + k0 + c);
        }
        __syncthreads();
        bf16x8 af = *(const bf16x8*)(sA + (wm + l16) * 40 + q * 8);
        bf16x8 bfr[6];
        #pragma unroll
        for (int j = 0; j < 6; j++)
            bfr[j] = *(const bf16x8*)(sB + (j * 16 + l16) * 40 + q * 8);
        #pragma unroll
        for (int j = 0; j < 6; j++)
            acc[j] = __builtin_amdgcn_mfma_f32_16x16x32_bf16(af, bfr[j], acc[j], 0, 0, 0);
    }

    int row0 = bm * 64 + wm + q * 4;
    #pragma unroll
    for (int j = 0; j < 6; j++)
        #pragma unroll
        for (int r = 0; r < 4; r++)
            atomicAdd(&xdbl[(size_t)(row0 + r) * 96 + j * 16 + l16], acc[j][r]);
}

// ---------- K4b: dt = softplus(xdbl[:, :64] @ dt_proj_w^T + b) -> bf16 ----------
__global__ __launch_bounds__(256) void dt_gemm_kernel(
    const float* __restrict__ xdbl, const ushort* __restrict__ dtwq,
    const float* __restrict__ dtb, ushort* __restrict__ dtout)
{
    __shared__ __align__(16) ushort sA[64 * 72];
    __shared__ __align__(16) ushort sB[64 * 72];
    int tid = threadIdx.x;
    int bm = blockIdx.x, bn = blockIdx.y;
    int wid = tid >> 6, lane = tid & 63;
    int wm = wid * 16;
    int l16 = lane & 15, q = lane >> 4;

    const float* Abase = xdbl + (size_t)bm * 64 * 96;
    const ushort* Bbase = dtwq + (size_t)bn * 64 * DT_RANK;
    #pragma unroll
    for (int i = tid; i < 512; i += 256) {
        int r = i >> 3, c = (i & 7) << 3;
        float4 v0 = *(const float4*)(Abase + (size_t)r * 96 + c);
        float4 v1 = *(const float4*)(Abase + (size_t)r * 96 + c + 4);
        ushort o[8] = {f2b(v0.x), f2b(v0.y), f2b(v0.z), f2b(v0.w),
                       f2b(v1.x), f2b(v1.y), f2b(v1.z), f2b(v1.w)};
        *(uint4*)(sA + r * 72 + c) = *(const uint4*)o;
        *(uint4*)(sB + r * 72 + c) = *(const uint4*)(Bbase + (size_t)r * DT_RANK + c);
    }
    __syncthreads();

    f32x4 acc[4];
    #pragma unroll
    for (int j = 0; j < 4; j++) acc[j] = (f32x4){0.f, 0.f, 0.f, 0.f};

    #pragma unroll
    for (int ks = 0; ks < 2; ks++) {
        bf16x8 af = *(const bf16x8*)(sA + (wm + l16) * 72 + ks * 32 + q * 8);
        bf16x8 bfr[4];
        #pragma unroll
        for (int j = 0; j < 4; j++)
            bfr[j] = *(const bf16x8*)(sB + (j * 16 + l16) * 72 + ks * 32 + q * 8);
        #pragma unroll
        for (int j = 0; j < 4; j++)
            acc[j] = __builtin_amdgcn_mfma_f32_16x16x32_bf16(af, bfr[j], acc[j], 0, 0, 0);
    }

    __syncthreads();
    #pragma unroll
    for (int j = 0; j < 4; j++) {
        float bias = dtb[bn * 64 + j * 16 + l16];
        #pragma unroll
        for (int r = 0; r < 4; r++) {
            float s = acc[j][r] + bias;
            float sp = (s > 20.f) ? s : log1pf(__expf(s));
            sA[(wm + q * 4 + r) * 72 + j * 16 + l16] = f2b(sp);
        }
    }
    __syncthreads();
    int row0 = bm * 64, col0 = bn * 64;
    #pragma unroll
    for (int rep = 0; rep < 2; rep++) {
        int off = rep * 2048 + tid * 8;
        int row = off >> 6, col = off & 63;
        *(uint4*)(dtout + (size_t)(row0 + row) * D_INNER + col0 + col) =
            *(const uint4*)(sA + row * 72 + col);
    }
}

// ---------- K5a: scan pass A — all-SSA float4 state (no scratch arrays) ----------
__global__ __launch_bounds__(256) void scan_partA_kernel(
    const ushort* __restrict__ dt, const ushort* __restrict__ xcq,
    const float* __restrict__ xdbl, const float* __restrict__ Alog,
    unsigned int* __restrict__ ch)
{
    __shared__ float sBC[LC][32];
    int bid = blockIdx.x;                  // 1024 = b(2) x chunk(64) x dgroup(8)
    int g = bid & 7;
    int c = (bid >> 3) & (NCH - 1);
    int b = bid >> 9;
    int tid = threadIdx.x;
    int lane = tid & 63, wid = tid >> 6;
    int d = g * 256 + wid * 64 + lane;
    int l0 = c * LC;

    if (tid < LC * 8) {                    // stage B/C tile (16 rows x 32 floats)
        int r = tid >> 3, c4 = (tid & 7) * 4;
        *(float4*)&sBC[r][c4] =
            *(const float4*)(xdbl + ((size_t)(b * LSEQ + l0 + r)) * 96 + 64 + c4);
    }
    const float4* Ap = (const float4*)(Alog + (size_t)d * D_STATE);
    float4 A0 = negexp4(Ap[0]), A1 = negexp4(Ap[1]);
    float4 A2 = negexp4(Ap[2]), A3 = negexp4(Ap[3]);
    __syncthreads();

    const ushort* dtp = dt  + ((size_t)(b * LSEQ + l0)) * D_INNER + d;
    const ushort* xcp = xcq + ((size_t)(b * LSEQ + l0)) * D_INNER + d;

    float4 h0 = {0.f, 0.f, 0.f, 0.f}, h1 = h0, h2 = h0, h3 = h0;
    float S = 0.f;                         // sum of dtv; prod a = exp2(A*S)

    for (int l = 0; l < LC; l++) {
        float dtv = b2f(dtp[(size_t)l * D_INNER]);
        float xcv = b2f(xcp[(size_t)l * D_INNER]);
        float t = dtv * xcv;
        S += dtv;
        float4 B0 = *(const float4*)&sBC[l][0];
        float4 B1 = *(const float4*)&sBC[l][4];
        float4 B2 = *(const float4*)&sBC[l][8];
        float4 B3 = *(const float4*)&sBC[l][12];
        SSTEP(h0, A0, B0); SSTEP(h1, A1, B1);
        SSTEP(h2, A2, B2); SSTEP(h3, A3, B3);
    }

    unsigned int* outp = ch + (((size_t)(c * 2 + b)) << 15) + (d << 4);
    uint4 v;
    v.x = packb2(fexp2(A0.x * S), h0.x); v.y = packb2(fexp2(A0.y * S), h0.y);
    v.z = packb2(fexp2(A0.z * S), h0.z); v.w = packb2(fexp2(A0.w * S), h0.w);
    *(uint4*)&outp[0] = v;
    v.x = packb2(fexp2(A1.x * S), h1.x); v.y = packb2(fexp2(A1.y * S), h1.y);
    v.z = packb2(fexp2(A1.z * S), h1.z); v.w = packb2(fexp2(A1.w * S), h1.w);
    *(uint4*)&outp[4] = v;
    v.x = packb2(fexp2(A2.x * S), h2.x); v.y = packb2(fexp2(A2.y * S), h2.y);
    v.z = packb2(fexp2(A2.z * S), h2.z); v.w = packb2(fexp2(A2.w * S), h2.w);
    *(uint4*)&outp[8] = v;
    v.x = packb2(fexp2(A3.x * S), h3.x); v.y = packb2(fexp2(A3.y * S), h3.y);
    v.z = packb2(fexp2(A3.z * S), h3.z); v.w = packb2(fexp2(A3.w * S), h3.w);
    *(uint4*)&outp[12] = v;
}

// ---------- K5b: stitch — bf16 ch in, bf16 h_init out ----------
__global__ __launch_bounds__(256) void scan_partB_kernel(
    const unsigned int* __restrict__ ch, ushort* __restrict__ hinit)
{
    int kk = blockIdx.x * 256 + threadIdx.x;   // 65536 = b(2) x dn(32768)
    int b = kk >> 15, dn = kk & 32767;
    float run = 0.f;
    #pragma unroll 8
    for (int c = 0; c < NCH; c++) {
        size_t off = (((size_t)(c * 2 + b)) << 15) + dn;
        unsigned int v = ch[off];
        hinit[off] = f2b(run);
        run = b2f((ushort)(v & 0xffffu)) * run + b2f((ushort)(v >> 16));
    }
}

// ---------- K5c: scan pass C — all-SSA float4 state, fused C-proj + gate ----------
__global__ __launch_bounds__(256) void scan_partC_kernel(
    const ushort* __restrict__ dt, const ushort* __restrict__ xcq,
    const float* __restrict__ xdbl, const ushort* __restrict__ zq,
    const float* __restrict__ Alog, const float* __restrict__ Dp,
    const ushort* __restrict__ hinit, ushort* __restrict__ yg)
{
    __shared__ float sBC[LC][32];
    int bid = blockIdx.x;
    int g = bid & 7;
    int c = (bid >> 3) & (NCH - 1);
    int b = bid >> 9;
    int tid = threadIdx.x;
    int lane = tid & 63, wid = tid >> 6;
    int d = g * 256 + wid * 64 + lane;
    int l0 = c * LC;

    if (tid < LC * 8) {
        int r = tid >> 3, c4 = (tid & 7) * 4;
        *(float4*)&sBC[r][c4] =
            *(const float4*)(xdbl + ((size_t)(b * LSEQ + l0 + r)) * 96 + 64 + c4);
    }
    const float4* Ap = (const float4*)(Alog + (size_t)d * D_STATE);
    float4 A0 = negexp4(Ap[0]), A1 = negexp4(Ap[1]);
    float4 A2 = negexp4(Ap[2]), A3 = negexp4(Ap[3]);
    float Dd = Dp[d];

    const ushort* hp = hinit + (((size_t)(c * 2 + b)) << 15) + (d << 4);
    ushort4 u0 = *(const ushort4*)(hp + 0);
    ushort4 u1 = *(const ushort4*)(hp + 4);
    ushort4 u2 = *(const ushort4*)(hp + 8);
    ushort4 u3 = *(const ushort4*)(hp + 12);
    float4 h0 = {b2f(u0.x), b2f(u0.y), b2f(u0.z), b2f(u0.w)};
    float4 h1 = {b2f(u1.x), b2f(u1.y), b2f(u1.z), b2f(u1.w)};
    float4 h2 = {b2f(u2.x), b2f(u2.y), b2f(u2.z), b2f(u2.w)};
    float4 h3 = {b2f(u3.x), b2f(u3.y), b2f(u3.z), b2f(u3.w)};
    __syncthreads();

    const ushort* dtp = dt  + ((size_t)(b * LSEQ + l0)) * D_INNER + d;
    const ushort* xcp = xcq + ((size_t)(b * LSEQ + l0)) * D_INNER + d;
    const ushort* zp  = zq  + ((size_t)(b * LSEQ + l0)) * D_INNER + d;
    ushort* yp = yg + ((size_t)(b * LSEQ + l0)) * D_INNER + d;

    for (int l = 0; l < LC; l++) {
        float dtv = b2f(dtp[(size_t)l * D_INNER]);
        float xcv = b2f(xcp[(size_t)l * D_INNER]);
        float zv  = b2f(zp[(size_t)l * D_INNER]);
        float t = dtv * xcv;
        float4 B0 = *(const float4*)&sBC[l][0];
        float4 B1 = *(const float4*)&sBC[l][4];
        float4 B2 = *(const float4*)&sBC[l][8];
        float4 B3 = *(const float4*)&sBC[l][12];
        float4 C0 = *(const float4*)&sBC[l][16];
        float4 C1 = *(const float4*)&sBC[l][20];
        float4 C2 = *(const float4*)&sBC[l][24];
        float4 C3 = *(const float4*)&sBC[l][28];
        float p0 = 0.f, p1 = 0.f, p2 = 0.f, p3 = 0.f;
        CSTEP(h0, A0, B0, C0); CSTEP(h1, A1, B1, C1);
        CSTEP(h2, A2, B2, C2); CSTEP(h3, A3, B3, C3);
        float p = (p0 + p1) + (p2 + p3);
        float y = p + Dd * xcv;
        float sz = zv / (1.f + __expf(-zv));
        yp[(size_t)l * D_INNER] = f2b(y * sz);
    }
}

extern "C" void kernel_launch(void* const* d_in, const int* in_sizes, int n_in,
                              void* d_out, int out_size, void* d_ws, size_t ws_size,
                              hipStream_t stream)
{
    const float* hs      = (const float*)d_in[0];
    const float* norm_w  = (const float*)d_in[1];
    const float* inproj  = (const float*)d_in[2];
    const float* convw   = (const float*)d_in[3];
    const float* convb   = (const float*)d_in[4];
    const float* xprojw  = (const float*)d_in[5];
    const float* dtw     = (const float*)d_in[6];
    const float* dtb     = (const float*)d_in[7];
    const float* alog    = (const float*)d_in[8];
    const float* dvec    = (const float*)d_in[9];
    const float* outproj = (const float*)d_in[10];

    float* out_main  = (float*)d_out;
    float* out_resid = (float*)d_out + (size_t)NTOK * D_MODEL;

    char* ws = (char*)d_ws;
    ushort*       xb    = (ushort*)(ws);                     // 384KB boundary rows
    ushort*       zq    = (ushort*)(ws +  8388608);          // 8.4MB
    ushort*       dtq   = (ushort*)(ws + 16777216);          // 8.4MB
    ushort*       xcb   = (ushort*)(ws + 25165824);          // 8.4MB
    unsigned int* ch    = (unsigned int*)(ws + 33554432);    // 16.8MB (bf16 ap,h)
    ushort*       hinit = (ushort*)(ws + 50331648);          // 8.4MB (bf16 h_init)
    float*        xdbl  = (float*) (ws + 67108864);          // 768KB
    ushort*       wIn   = (ushort*)(ws + 67895296);          // 8.4MB
    ushort*       wOut  = (ushort*)(ws + 76283904);          // 4.2MB
    ushort*       h_bf16= (ushort*)(ws + 80478208);          // 4.2MB
    ushort*       xpw_b = (ushort*)(ws + 84672512);          // 384KB
    ushort*       dtw_b = (ushort*)(ws + 85065728);          // 256KB
    ushort*       yg_bf16=(ushort*)(ws + 85327872);          // 8.4MB (end ~93.7MB)

    // K0: prep = rmsnorm + weight cvts + xdbl zero + out zero
    prep_kernel<<<NTOK + 6464 + 192 + 2048, 256, 0, stream>>>(
        hs, norm_w, h_bf16, out_resid,
        inproj, outproj, xprojw, dtw, wIn, wOut, xpw_b, dtw_b, xdbl, out_main);

    // K2: xz GEMM (512 thr, 8 waves) + fused conv/SiLU (x-half) -> xcb, zq, xb
    gemm_xz_kernel<<<dim3(NTOK / 128, (2 * D_INNER) / 128), 512, 0, stream>>>(
        h_bf16, wIn, convw, convb, xcb, xb, zq, D_MODEL);

    // K2b: finish conv for first 3 rows of each 128-token tile
    conv_fixup_kernel<<<48, 256, 0, stream>>>(xb, convw, convb, xcb);

    // K4a: x_dbl GEMM — split-K, 64-row tiles (512 blocks = 2/CU), atomics
    xproj_partial_kernel<<<dim3(NTOK / 64, KSL), 256, 0, stream>>>(
        xcb, xpw_b, xdbl);

    // K4b: dt GEMM (A staged from f32 xdbl) + bias + softplus -> bf16
    dt_gemm_kernel<<<dim3(NTOK / 64, D_INNER / 64), 256, 0, stream>>>(
        xdbl, dtw_b, dtb, dtq);

    // K5: chunked parallel scan, NCH=64 (4 blocks/CU), bf16-packed stitch
    scan_partA_kernel<<<1024, 256, 0, stream>>>(dtq, xcb, xdbl, alog, ch);
    scan_partB_kernel<<<256, 256, 0, stream>>>(ch, hinit);
    scan_partC_kernel<<<1024, 256, 0, stream>>>(dtq, xcb, xdbl, zq,
                                                alog, dvec, hinit, yg_bf16);

    // K6: out = yg @ out_proj_w^T, 64x64 split-K=2 (1024 blocks = 4/CU)
    gemm64_kernel<<<dim3(NTOK / 64, D_MODEL / 64, 2), 256, 0, stream>>>(
        yg_bf16, wOut, out_main, NTOK, D_MODEL, D_INNER);
}

// Round 14
// 235.395 us; speedup vs baseline: 2.0507x; 1.0008x over previous
//
#include <hip/hip_runtime.h>

// ---------- common helpers ----------
typedef __bf16 bf16x8 __attribute__((ext_vector_type(8)));
typedef float f32x4 __attribute__((ext_vector_type(4)));

__device__ __forceinline__ float b2f(ushort u) {
    union { unsigned int i; float f; } v;
    v.i = ((unsigned int)u) << 16;
    return v.f;
}
__device__ __forceinline__ ushort f2b(float f) {
    union { float f; unsigned int i; } v;
    v.f = f;
    unsigned int x = v.i;
    unsigned int r = (x + 0x7fffu + ((x >> 16) & 1u)) >> 16;
    return (ushort)r;
}
__device__ __forceinline__ float fexp2(float x) {
#if __has_builtin(__builtin_amdgcn_exp2f)
    return __builtin_amdgcn_exp2f(x);
#else
    return exp2f(x);
#endif
}
// pack (ap,h) as bf16 pair: lo=ap, hi=h
__device__ __forceinline__ unsigned int packb2(float ap, float h) {
    return ((unsigned int)f2b(h) << 16) | (unsigned int)f2b(ap);
}
// async 16B global->LDS; lane i lands at lds + i*16B (wave-uniform base)
__device__ __forceinline__ void gload16(const ushort* g, ushort* l) {
    __builtin_amdgcn_global_load_lds(
        (const __attribute__((address_space(1))) unsigned int*)g,
        (__attribute__((address_space(3))) unsigned int*)l, 16, 0, 0);
}
// LDS fragment read with XOR chunk swizzle (row stride 64 ushorts, 8 chunks of 8)
__device__ __forceinline__ bf16x8 ldsfrag(const ushort* s, int row, int cq) {
    int p = cq ^ (row & 7);
    return *(const bf16x8*)(s + row * 64 + p * 8);
}

#define D_MODEL 1024
#define D_INNER 2048
#define D_STATE 16
#define DT_RANK 64
#define NTOK    2048   // B*L
#define LSEQ    1024
#define NCH     64     // scan chunks (64: 4 blocks/CU for latency hiding)
#define LC      16     // steps per chunk
#define KSL     16     // xproj K-slices
#define LOG2E   1.44269504088896f

// ---------- K0: prep = RMSNorm + weight cvts + xdbl zero + out zero ----------
__global__ __launch_bounds__(256) void prep_kernel(
    const float* __restrict__ hs, const float* __restrict__ w,
    ushort* __restrict__ hout, float* __restrict__ resid,
    const float* __restrict__ inproj, const float* __restrict__ outproj,
    const float* __restrict__ xprojw, const float* __restrict__ dtw,
    ushort* __restrict__ wIn, ushort* __restrict__ wOut,
    ushort* __restrict__ xpw, ushort* __restrict__ dtwb,
    float* __restrict__ xdbl, float* __restrict__ outz)
{
    int blk = blockIdx.x;
    int tid = threadIdx.x;
    if (blk < NTOK) {
        int t = blk;
        float4 r4 = *(const float4*)(hs + (size_t)t * D_MODEL + tid * 4);
        float s = r4.x * r4.x + r4.y * r4.y + r4.z * r4.z + r4.w * r4.w;
        #pragma unroll
        for (int off = 32; off >= 1; off >>= 1) s += __shfl_xor(s, off);
        __shared__ float red[4];
        int lane = tid & 63, wid = tid >> 6;
        if (lane == 0) red[wid] = s;
        __syncthreads();
        float tot = red[0] + red[1] + red[2] + red[3];
        float inv = 1.0f / (sqrtf(tot) * (1.0f / 32.0f) + 1e-5f);
        float4 w4 = *(const float4*)(w + tid * 4);
        ushort4 o;
        o.x = f2b(w4.x * r4.x * inv);
        o.y = f2b(w4.y * r4.y * inv);
        o.z = f2b(w4.z * r4.z * inv);
        o.w = f2b(w4.w * r4.w * inv);
        *(ushort4*)(hout + (size_t)t * D_MODEL + tid * 4) = o;
        *(float4*)(resid + (size_t)t * D_MODEL + tid * 4) = r4;   // exact copy
    } else if (blk < NTOK + 6464) {
        int i = (blk - NTOK) * 256 + tid;
        const float* src; ushort* dst; int off;
        if (i < 1048576)      { src = inproj;  dst = wIn;  off = i; }
        else if (i < 1572864) { src = outproj; dst = wOut; off = i - 1048576; }
        else if (i < 1622016) { src = xprojw;  dst = xpw;  off = i - 1572864; }
        else if (i < 1654784) { src = dtw;     dst = dtwb; off = i - 1622016; }
        else return;
        float4 v = *(const float4*)(src + (size_t)off * 4);
        ushort4 o;
        o.x = f2b(v.x); o.y = f2b(v.y); o.z = f2b(v.z); o.w = f2b(v.w);
        *(ushort4*)(dst + (size_t)off * 4) = o;
    } else if (blk < NTOK + 6464 + 192) {
        int i = (blk - NTOK - 6464) * 256 + tid;   // 49152 float4s = 196608 floats
        if (i < 49152)
            *(float4*)(xdbl + (size_t)i * 4) = (float4){0.f, 0.f, 0.f, 0.f};
    } else {
        int i = (blk - NTOK - 6464 - 192) * 256 + tid;  // 524288 float4s = out f32
        if (i < 524288)
            *(float4*)(outz + (size_t)i * 4) = (float4){0.f, 0.f, 0.f, 0.f};
    }
}

// ---------- K2: xz GEMM 128x128, 8 waves, DOUBLE-BUFFERED 2-phase pipeline ----------
// LDS = 64KB: A0/B0/A1/B1 (16KB each). Per K-step: issue stage(next) BEFORE
// compute(cur); single __syncthreads (vmcnt drain lands after MFMA covers the
// load latency). 18 barriers vs 33. Conv weights in registers (fixed chunk).
__global__ __launch_bounds__(512) void gemm_xz_kernel(
    const ushort* __restrict__ Ag, const ushort* __restrict__ Wg,
    const float* __restrict__ cw, const float* __restrict__ cb,
    ushort* __restrict__ xcb, ushort* __restrict__ xb,
    ushort* __restrict__ zq, int K)
{
    __shared__ __align__(16) ushort smem[4 * 8192];   // 64KB
    ushort* A0 = smem;
    ushort* B0 = smem + 8192;
    ushort* A1 = smem + 16384;
    ushort* B1 = smem + 24576;
    int tid = threadIdx.x;
    int bm = blockIdx.x, bn = blockIdx.y;
    int wid = tid >> 6, lane = tid & 63;
    int wm = (wid >> 1) * 32, wn = (wid & 1) * 64;   // wave owns 32x64
    int l16 = lane & 15, q = lane >> 4;
    int colbase = (bn & 15) * 128;

    f32x4 acc[2][4];
    #pragma unroll
    for (int i = 0; i < 2; i++)
        #pragma unroll
        for (int j = 0; j < 4; j++)
            acc[i][j] = (f32x4){0.f, 0.f, 0.f, 0.f};

    const ushort* Abase = Ag + (size_t)bm * 128 * K;
    const ushort* Wbase = Wg + (size_t)bn * 128 * K;

    int segr = lane >> 3, segc = lane & 7;
    size_t goff[2]; int sseg[2];
    #pragma unroll
    for (int t = 0; t < 2; t++) {          // 16 segs each for A and B, 8 wids x 2
        int s = wid * 2 + t;
        int r = s * 8 + segr;
        int gc = segc ^ (r & 7);
        sseg[t] = s * 512;
        goff[t] = (size_t)r * K + gc * 8;
    }

    // prologue: stage K-step 0 into buf0
    #pragma unroll
    for (int t = 0; t < 2; t++) {
        gload16(Abase + goff[t], A0 + sseg[t]);
        gload16(Wbase + goff[t], B0 + sseg[t]);
    }
    __syncthreads();

    for (int step = 0; step < 16; step++) {
        const ushort* cA = (step & 1) ? A1 : A0;
        const ushort* cB = (step & 1) ? B1 : B0;
        if (step < 15) {                   // issue next-tile loads first
            ushort* nA = (step & 1) ? A0 : A1;
            ushort* nB = (step & 1) ? B0 : B1;
            size_t k0n = (size_t)(step + 1) * 64;
            #pragma unroll
            for (int t = 0; t < 2; t++) {
                gload16(Abase + goff[t] + k0n, nA + sseg[t]);
                gload16(Wbase + goff[t] + k0n, nB + sseg[t]);
            }
        }
        #pragma unroll
        for (int ks = 0; ks < 2; ks++) {
            int cq = ks * 4 + q;
            bf16x8 af[2], bfr[4];
            #pragma unroll
            for (int i = 0; i < 2; i++)
                af[i] = ldsfrag(cA, wm + i * 16 + l16, cq);
            #pragma unroll
            for (int j = 0; j < 4; j++)
                bfr[j] = ldsfrag(cB, wn + j * 16 + l16, cq);
            #pragma unroll
            for (int i = 0; i < 2; i++)
                #pragma unroll
                for (int j = 0; j < 4; j++)
                    acc[i][j] = __builtin_amdgcn_mfma_f32_16x16x32_bf16(af[i], bfr[j], acc[i][j], 0, 0, 0);
        }
        __syncthreads();                   // drains vmcnt (stage) + barrier
    }

    // repack bf16 C tile into smem[0..16384) (chunk-XOR vs row)
    #pragma unroll
    for (int i = 0; i < 2; i++)
        #pragma unroll
        for (int j = 0; j < 4; j++) {
            int col = wn + j * 16 + l16;
            int cchunk = col >> 3, cin = col & 7;
            #pragma unroll
            for (int r = 0; r < 4; r++) {
                int row = wm + i * 16 + q * 4 + r;
                smem[row * 128 + ((cchunk ^ (row & 7)) << 3) + cin] =
                    f2b(acc[i][j][r]);
            }
        }
    __syncthreads();
    size_t rowbase = (size_t)bm * 128;

    if (bn >= 16) {                        // z-half: plain coalesced store
        int cb2 = (bn - 16) * 128;
        #pragma unroll
        for (int it = 0; it < 4; it++) {
            int flat = it * 4096 + tid * 8;
            int row = flat >> 7, cchunk = (flat & 127) >> 3;
            *(uint4*)(zq + (rowbase + row) * D_INNER + cb2 + (cchunk << 3)) =
                *(const uint4*)(smem + row * 128 + ((cchunk ^ (row & 7)) << 3));
        }
        return;
    }

    // x-half: save raw boundary rows {0,1,2,125,126,127} for the fixup kernel
    if (tid < 96) {
        int rr = tid >> 4;                 // 0..5
        int row = (rr < 3) ? rr : (125 + rr - 3);
        int chunk = tid & 15;
        *(uint4*)(xb + (size_t)(bm * 6 + rr) * D_INNER + colbase + chunk * 8) =
            *(const uint4*)(smem + row * 128 + ((chunk ^ (row & 7)) << 3));
    }

    // fused conv+SiLU rows 3..127; each thread owns FIXED chunk (tid&15),
    // conv weights for its 8 columns in registers (loaded once from global).
    int mych = tid & 15;
    int rgrp = tid >> 4;                   // 0..31
    float4 w4[8]; float bias[8];
    #pragma unroll
    for (int j = 0; j < 8; j++) {
        w4[j] = *(const float4*)(cw + (size_t)(colbase + mych * 8 + j) * 4);
        bias[j] = cb[colbase + mych * 8 + j];
    }
    #pragma unroll
    for (int it = 0; it < 4; it++) {
        int row = 3 + rgrp + it * 32;
        if (row < 128) {
            ushort tap[4][8];
            #pragma unroll
            for (int k = 0; k < 4; k++) {
                int rk = row - 3 + k;
                *(uint4*)tap[k] =
                    *(const uint4*)(smem + rk * 128 + ((mych ^ (rk & 7)) << 3));
            }
            ushort o[8];
            #pragma unroll
            for (int j = 0; j < 8; j++) {
                float a2 = bias[j];
                a2 += b2f(tap[0][j]) * w4[j].x;
                a2 += b2f(tap[1][j]) * w4[j].y;
                a2 += b2f(tap[2][j]) * w4[j].z;
                a2 += b2f(tap[3][j]) * w4[j].w;
                o[j] = f2b(a2 / (1.f + __expf(-a2)));
            }
            *(uint4*)(xcb + (rowbase + row) * D_INNER + colbase + mych * 8) =
                *(const uint4*)o;
        }
    }
}

// ---------- K2b: conv fixup for rows 0..2 of each 128-token tile (48 tokens) ----------
__global__ __launch_bounds__(256) void conv_fixup_kernel(
    const ushort* __restrict__ xb, const float* __restrict__ cw,
    const float* __restrict__ cb, ushort* __restrict__ xcb)
{
    int bm = blockIdx.x / 3;               // 0..15
    int r  = blockIdx.x % 3;               // 0..2
    int d0 = threadIdx.x * 8;

    ushort tap[4][8];
    bool has[4];
    #pragma unroll
    for (int k = 0; k < 4; k++) {
        int rt = r - 3 + k;                // token offset within tile, may be <0
        if (rt < 0 && (bm & 7) == 0) {     // l = r here -> causal zero-pad
            has[k] = false;
        } else {
            has[k] = true;
            int bmm, slot;
            if (rt < 0) { bmm = bm - 1; slot = rt + 6; }   // prev rows 125..127 -> 3..5
            else        { bmm = bm;     slot = rt; }       // own rows 0..2
            *(uint4*)tap[k] =
                *(const uint4*)(xb + (size_t)(bmm * 6 + slot) * D_INNER + d0);
        }
    }
    ushort o[8];
    #pragma unroll
    for (int j = 0; j < 8; j++) {
        float4 w4 = *(const float4*)(cw + (size_t)(d0 + j) * 4);
        float wk[4] = {w4.x, w4.y, w4.z, w4.w};
        float acc = cb[d0 + j];
        #pragma unroll
        for (int k = 0; k < 4; k++)
            if (has[k]) acc += b2f(tap[k][j]) * wk[k];
        o[j] = f2b(acc / (1.f + __expf(-acc)));
    }
    *(uint4*)(xcb + (size_t)(bm * 128 + r) * D_INNER + d0) = *(const uint4*)o;
}

// ---------- K6: 64x64 GEMM, split-K=2 (4 blocks/CU), f32 atomic epilogue ----------
__global__ __launch_bounds__(256) void gemm64_kernel(
    const ushort* __restrict__ Ag, const ushort* __restrict__ Wg,
    float* __restrict__ Cf, int M, int N, int K)
{
    __shared__ __align__(16) ushort sA[64 * 64];
    __shared__ __align__(16) ushort sB[64 * 64];
    int tid = threadIdx.x;
    int bm = blockIdx.x, bn = blockIdx.y, bz = blockIdx.z;
    int wid = tid >> 6, lane = tid & 63;
    int wm = wid * 16;
    int l16 = lane & 15, q = lane >> 4;

    f32x4 acc[4];
    #pragma unroll
    for (int j = 0; j < 4; j++) acc[j] = (f32x4){0.f, 0.f, 0.f, 0.f};

    const ushort* Abase = Ag + (size_t)bm * 64 * K;
    const ushort* Wbase = Wg + (size_t)bn * 64 * K;

    int segr = lane >> 3, segc = lane & 7;
    size_t goff[2]; int sseg[2];
    #pragma unroll
    for (int t = 0; t < 2; t++) {
        int s = wid * 2 + t;
        int r = s * 8 + segr;
        int gc = segc ^ (r & 7);
        sseg[t] = s * 512;
        goff[t] = (size_t)r * K + gc * 8;
    }

    int kbeg = bz * (K / 2), kend = kbeg + K / 2;
    for (int k0 = kbeg; k0 < kend; k0 += 64) {
        __syncthreads();
        #pragma unroll
        for (int t = 0; t < 2; t++) {
            gload16(Abase + goff[t] + k0, sA + sseg[t]);
            gload16(Wbase + goff[t] + k0, sB + sseg[t]);
        }
        __syncthreads();
        #pragma unroll
        for (int ks = 0; ks < 2; ks++) {
            int cq = ks * 4 + q;
            bf16x8 af = ldsfrag(sA, wm + l16, cq);
            bf16x8 bfr[4];
            #pragma unroll
            for (int j = 0; j < 4; j++)
                bfr[j] = ldsfrag(sB, j * 16 + l16, cq);
            #pragma unroll
            for (int j = 0; j < 4; j++)
                acc[j] = __builtin_amdgcn_mfma_f32_16x16x32_bf16(af, bfr[j], acc[j], 0, 0, 0);
        }
    }

    int row0 = bm * 64 + wm + q * 4;
    int col0 = bn * 64 + l16;
    #pragma unroll
    for (int j = 0; j < 4; j++)
        #pragma unroll
        for (int r = 0; r < 4; r++)
            atomicAdd(&Cf[(size_t)(row0 + r) * N + col0 + j * 16], acc[j][r]);
}

// ---------- K4a: xproj split-K partial GEMM, 64-row tiles (2 blocks/CU) ----------
__global__ __launch_bounds__(256) void xproj_partial_kernel(
    const ushort* __restrict__ xcb, const ushort* __restrict__ wq,
    float* __restrict__ xdbl)
{
    __shared__ __align__(16) ushort sA[64 * 40];
    __shared__ __align__(16) ushort sB[96 * 40];
    int tid = threadIdx.x;
    int bm = blockIdx.x, sl = blockIdx.y;    // bm<32 (64-row tiles), sl<16
    int wid = tid >> 6, lane = tid & 63;
    int wm = wid * 16;
    int l16 = lane & 15, q = lane >> 4;

    f32x4 acc[6];
    #pragma unroll
    for (int j = 0; j < 6; j++)
        acc[j] = (f32x4){0.f, 0.f, 0.f, 0.f};

    const ushort* Abase = xcb + (size_t)bm * 64 * D_INNER;
    int kbase = sl * (D_INNER / KSL);

    for (int kk = 0; kk < D_INNER / KSL; kk += 32) {
        int k0 = kbase + kk;
        __syncthreads();
        {
            int r = tid >> 2, c = (tid & 3) << 3;   // 256 uint4 = 64 rows x 32 cols
            *(uint4*)(sA + r * 40 + c) = *(const uint4*)(Abase + (size_t)r * D_INNER + k0 + c);
        }
        for (int i = tid; i < 384; i += 256) {
            int r = i >> 2, c = (i & 3) << 3;
            *(uint4*)(sB + r * 40 + c) = *(const uint4*)(wq + (size_t)r * D_INNER + k0 + c);
        }
        __syncthreads();
        bf16x8 af = *(const bf16x8*)(sA + (wm + l16) * 40 + q * 8);
        bf16x8 bfr[6];
        #pragma unroll
        for (int j = 0; j < 6; j++)
            bfr[j] = *(const bf16x8*)(sB + (j * 16 + l16) * 40 + q * 8);
        #pragma unroll
        for (int j = 0; j < 6; j++)
            acc[j] = __builtin_amdgcn_mfma_f32_16x16x32_bf16(af, bfr[j], acc[j], 0, 0, 0);
    }

    int row0 = bm * 64 + wm + q * 4;
    #pragma unroll
    for (int j = 0; j < 6; j++)
        #pragma unroll
        for (int r = 0; r < 4; r++)
            atomicAdd(&xdbl[(size_t)(row0 + r) * 96 + j * 16 + l16], acc[j][r]);
}

// ---------- K4b: dt = softplus(xdbl[:, :64] @ dt_proj_w^T + b) -> bf16 ----------
__global__ __launch_bounds__(256) void dt_gemm_kernel(
    const float* __restrict__ xdbl, const ushort* __restrict__ dtwq,
    const float* __restrict__ dtb, ushort* __restrict__ dtout)
{
    __shared__ __align__(16) ushort sA[64 * 72];
    __shared__ __align__(16) ushort sB[64 * 72];
    int tid = threadIdx.x;
    int bm = blockIdx.x, bn = blockIdx.y;
    int wid = tid >> 6, lane = tid & 63;
    int wm = wid * 16;
    int l16 = lane & 15, q = lane >> 4;

    const float* Abase = xdbl + (size_t)bm * 64 * 96;
    const ushort* Bbase = dtwq + (size_t)bn * 64 * DT_RANK;
    #pragma unroll
    for (int i = tid; i < 512; i += 256) {
        int r = i >> 3, c = (i & 7) << 3;
        float4 v0 = *(const float4*)(Abase + (size_t)r * 96 + c);
        float4 v1 = *(const float4*)(Abase + (size_t)r * 96 + c + 4);
        ushort o[8] = {f2b(v0.x), f2b(v0.y), f2b(v0.z), f2b(v0.w),
                       f2b(v1.x), f2b(v1.y), f2b(v1.z), f2b(v1.w)};
        *(uint4*)(sA + r * 72 + c) = *(const uint4*)o;
        *(uint4*)(sB + r * 72 + c) = *(const uint4*)(Bbase + (size_t)r * DT_RANK + c);
    }
    __syncthreads();

    f32x4 acc[4];
    #pragma unroll
    for (int j = 0; j < 4; j++) acc[j] = (f32x4){0.f, 0.f, 0.f, 0.f};

    #pragma unroll
    for (int ks = 0; ks < 2; ks++) {
        bf16x8 af = *(const bf16x8*)(sA + (wm + l16) * 72 + ks * 32 + q * 8);
        bf16x8 bfr[4];
        #pragma unroll
        for (int j = 0; j < 4; j++)
            bfr[j] = *(const bf16x8*)(sB + (j * 16 + l16) * 72 + ks * 32 + q * 8);
        #pragma unroll
        for (int j = 0; j < 4; j++)
            acc[j] = __builtin_amdgcn_mfma_f32_16x16x32_bf16(af, bfr[j], acc[j], 0, 0, 0);
    }

    __syncthreads();
    #pragma unroll
    for (int j = 0; j < 4; j++) {
        float bias = dtb[bn * 64 + j * 16 + l16];
        #pragma unroll
        for (int r = 0; r < 4; r++) {
            float s = acc[j][r] + bias;
            float sp = (s > 20.f) ? s : log1pf(__expf(s));
            sA[(wm + q * 4 + r) * 72 + j * 16 + l16] = f2b(sp);
        }
    }
    __syncthreads();
    int row0 = bm * 64, col0 = bn * 64;
    #pragma unroll
    for (int rep = 0; rep < 2; rep++) {
        int off = rep * 2048 + tid * 8;
        int row = off >> 6, col = off & 63;
        *(uint4*)(dtout + (size_t)(row0 + row) * D_INNER + col0 + col) =
            *(const uint4*)(sA + row * 72 + col);
    }
}

// ---------- K5a: scan pass A — lane-owns-d, NCH=64, bf16-packed (ap,h) ----------
__global__ __launch_bounds__(256) void scan_partA_kernel(
    const ushort* __restrict__ dt, const ushort* __restrict__ xcq,
    const float* __restrict__ xdbl, const float* __restrict__ Alog,
    unsigned int* __restrict__ ch)
{
    __shared__ float sBC[LC][32];
    int bid = blockIdx.x;                  // 1024 = b(2) x chunk(64) x dgroup(8)
    int g = bid & 7;
    int c = (bid >> 3) & (NCH - 1);
    int b = bid >> 9;
    int tid = threadIdx.x;
    int lane = tid & 63, wid = tid >> 6;
    int d = g * 256 + wid * 64 + lane;
    int l0 = c * LC;

    if (tid < LC * 8) {                    // stage B/C tile (16 rows x 32 floats)
        int r = tid >> 3, c4 = (tid & 7) * 4;
        *(float4*)&sBC[r][c4] =
            *(const float4*)(xdbl + ((size_t)(b * LSEQ + l0 + r)) * 96 + 64 + c4);
    }
    float A[16];
    #pragma unroll
    for (int k = 0; k < 4; k++)
        *(float4*)&A[k * 4] = *(const float4*)(Alog + d * D_STATE + k * 4);
    #pragma unroll
    for (int n = 0; n < 16; n++) A[n] = -__expf(A[n]) * LOG2E;
    __syncthreads();

    const ushort* dtp = dt  + ((size_t)(b * LSEQ + l0)) * D_INNER + d;
    const ushort* xcp = xcq + ((size_t)(b * LSEQ + l0)) * D_INNER + d;

    float h[16];
    #pragma unroll
    for (int n = 0; n < 16; n++) h[n] = 0.f;
    float S = 0.f;                         // sum of dtv; prod a = exp2(A*S)

    for (int l = 0; l < LC; l++) {
        float dtv = b2f(dtp[(size_t)l * D_INNER]);
        float xcv = b2f(xcp[(size_t)l * D_INNER]);
        float t = dtv * xcv;
        S += dtv;
        float Bv[16];
        #pragma unroll
        for (int k = 0; k < 4; k++)
            *(float4*)&Bv[k * 4] = *(const float4*)&sBC[l][k * 4];
        #pragma unroll
        for (int n = 0; n < 16; n++) {
            float a = fexp2(dtv * A[n]);
            h[n] = h[n] * a + t * Bv[n];
        }
    }

    unsigned int* outp = ch + (((size_t)(c * 2 + b)) << 15) + (d << 4);
    #pragma unroll
    for (int n = 0; n < 16; n += 4) {
        uint4 v;
        v.x = packb2(fexp2(A[n] * S),     h[n]);
        v.y = packb2(fexp2(A[n + 1] * S), h[n + 1]);
        v.z = packb2(fexp2(A[n + 2] * S), h[n + 2]);
        v.w = packb2(fexp2(A[n + 3] * S), h[n + 3]);
        *(uint4*)&outp[n] = v;
    }
}

// ---------- K5b: stitch — bf16 ch in, bf16 h_init out ----------
__global__ __launch_bounds__(256) void scan_partB_kernel(
    const unsigned int* __restrict__ ch, ushort* __restrict__ hinit)
{
    int kk = blockIdx.x * 256 + threadIdx.x;   // 65536 = b(2) x dn(32768)
    int b = kk >> 15, dn = kk & 32767;
    float run = 0.f;
    #pragma unroll 8
    for (int c = 0; c < NCH; c++) {
        size_t off = (((size_t)(c * 2 + b)) << 15) + dn;
        unsigned int v = ch[off];
        hinit[off] = f2b(run);
        run = b2f((ushort)(v & 0xffffu)) * run + b2f((ushort)(v >> 16));
    }
}

// ---------- K5c: scan pass C — lane-owns-d, fused C-proj + D-skip + gate ----------
__global__ __launch_bounds__(256) void scan_partC_kernel(
    const ushort* __restrict__ dt, const ushort* __restrict__ xcq,
    const float* __restrict__ xdbl, const ushort* __restrict__ zq,
    const float* __restrict__ Alog, const float* __restrict__ Dp,
    const ushort* __restrict__ hinit, ushort* __restrict__ yg)
{
    __shared__ float sBC[LC][32];
    int bid = blockIdx.x;
    int g = bid & 7;
    int c = (bid >> 3) & (NCH - 1);
    int b = bid >> 9;
    int tid = threadIdx.x;
    int lane = tid & 63, wid = tid >> 6;
    int d = g * 256 + wid * 64 + lane;
    int l0 = c * LC;

    if (tid < LC * 8) {
        int r = tid >> 3, c4 = (tid & 7) * 4;
        *(float4*)&sBC[r][c4] =
            *(const float4*)(xdbl + ((size_t)(b * LSEQ + l0 + r)) * 96 + 64 + c4);
    }
    float A[16];
    #pragma unroll
    for (int k = 0; k < 4; k++)
        *(float4*)&A[k * 4] = *(const float4*)(Alog + d * D_STATE + k * 4);
    #pragma unroll
    for (int n = 0; n < 16; n++) A[n] = -__expf(A[n]) * LOG2E;
    float Dd = Dp[d];

    const ushort* hp = hinit + (((size_t)(c * 2 + b)) << 15) + (d << 4);
    float h[16];
    #pragma unroll
    for (int n = 0; n < 16; n += 4) {
        ushort4 v = *(const ushort4*)(hp + n);
        h[n] = b2f(v.x); h[n + 1] = b2f(v.y);
        h[n + 2] = b2f(v.z); h[n + 3] = b2f(v.w);
    }
    __syncthreads();

    const ushort* dtp = dt  + ((size_t)(b * LSEQ + l0)) * D_INNER + d;
    const ushort* xcp = xcq + ((size_t)(b * LSEQ + l0)) * D_INNER + d;
    const ushort* zp  = zq  + ((size_t)(b * LSEQ + l0)) * D_INNER + d;
    ushort* yp = yg + ((size_t)(b * LSEQ + l0)) * D_INNER + d;

    for (int l = 0; l < LC; l++) {
        float dtv = b2f(dtp[(size_t)l * D_INNER]);
        float xcv = b2f(xcp[(size_t)l * D_INNER]);
        float zv  = b2f(zp[(size_t)l * D_INNER]);
        float t = dtv * xcv;
        float Bv[16], Cv[16];
        #pragma unroll
        for (int k = 0; k < 4; k++) {
            *(float4*)&Bv[k * 4] = *(const float4*)&sBC[l][k * 4];
            *(float4*)&Cv[k * 4] = *(const float4*)&sBC[l][16 + k * 4];
        }
        float p0 = 0.f, p1 = 0.f, p2 = 0.f, p3 = 0.f;
        #pragma unroll
        for (int n = 0; n < 16; n += 4) {
            float a0 = fexp2(dtv * A[n]);
            float a1 = fexp2(dtv * A[n + 1]);
            float a2 = fexp2(dtv * A[n + 2]);
            float a3 = fexp2(dtv * A[n + 3]);
            h[n]     = h[n] * a0 + t * Bv[n];
            h[n + 1] = h[n + 1] * a1 + t * Bv[n + 1];
            h[n + 2] = h[n + 2] * a2 + t * Bv[n + 2];
            h[n + 3] = h[n + 3] * a3 + t * Bv[n + 3];
            p0 += h[n] * Cv[n];
            p1 += h[n + 1] * Cv[n + 1];
            p2 += h[n + 2] * Cv[n + 2];
            p3 += h[n + 3] * Cv[n + 3];
        }
        float p = (p0 + p1) + (p2 + p3);
        float y = p + Dd * xcv;
        float sz = zv / (1.f + __expf(-zv));
        yp[(size_t)l * D_INNER] = f2b(y * sz);
    }
}

extern "C" void kernel_launch(void* const* d_in, const int* in_sizes, int n_in,
                              void* d_out, int out_size, void* d_ws, size_t ws_size,
                              hipStream_t stream)
{
    const float* hs      = (const float*)d_in[0];
    const float* norm_w  = (const float*)d_in[1];
    const float* inproj  = (const float*)d_in[2];
    const float* convw   = (const float*)d_in[3];
    const float* convb   = (const float*)d_in[4];
    const float* xprojw  = (const float*)d_in[5];
    const float* dtw     = (const float*)d_in[6];
    const float* dtb     = (const float*)d_in[7];
    const float* alog    = (const float*)d_in[8];
    const float* dvec    = (const float*)d_in[9];
    const float* outproj = (const float*)d_in[10];

    float* out_main  = (float*)d_out;
    float* out_resid = (float*)d_out + (size_t)NTOK * D_MODEL;

    char* ws = (char*)d_ws;
    ushort*       xb    = (ushort*)(ws);                     // 384KB boundary rows
    ushort*       zq    = (ushort*)(ws +  8388608);          // 8.4MB
    ushort*       dtq   = (ushort*)(ws + 16777216);          // 8.4MB
    ushort*       xcb   = (ushort*)(ws + 25165824);          // 8.4MB
    unsigned int* ch    = (unsigned int*)(ws + 33554432);    // 16.8MB (bf16 ap,h)
    ushort*       hinit = (ushort*)(ws + 50331648);          // 8.4MB (bf16 h_init)
    float*        xdbl  = (float*) (ws + 67108864);          // 768KB
    ushort*       wIn   = (ushort*)(ws + 67895296);          // 8.4MB
    ushort*       wOut  = (ushort*)(ws + 76283904);          // 4.2MB
    ushort*       h_bf16= (ushort*)(ws + 80478208);          // 4.2MB
    ushort*       xpw_b = (ushort*)(ws + 84672512);          // 384KB
    ushort*       dtw_b = (ushort*)(ws + 85065728);          // 256KB
    ushort*       yg_bf16=(ushort*)(ws + 85327872);          // 8.4MB (end ~93.7MB)

    // K0: prep = rmsnorm + weight cvts + xdbl zero + out zero
    prep_kernel<<<NTOK + 6464 + 192 + 2048, 256, 0, stream>>>(
        hs, norm_w, h_bf16, out_resid,
        inproj, outproj, xprojw, dtw, wIn, wOut, xpw_b, dtw_b, xdbl, out_main);

    // K2: xz GEMM (512 thr, double-buffered 2-phase) + fused conv/SiLU
    gemm_xz_kernel<<<dim3(NTOK / 128, (2 * D_INNER) / 128), 512, 0, stream>>>(
        h_bf16, wIn, convw, convb, xcb, xb, zq, D_MODEL);

    // K2b: finish conv for first 3 rows of each 128-token tile
    conv_fixup_kernel<<<48, 256, 0, stream>>>(xb, convw, convb, xcb);

    // K4a: x_dbl GEMM — split-K, 64-row tiles (512 blocks = 2/CU), atomics
    xproj_partial_kernel<<<dim3(NTOK / 64, KSL), 256, 0, stream>>>(
        xcb, xpw_b, xdbl);

    // K4b: dt GEMM (A staged from f32 xdbl) + bias + softplus -> bf16
    dt_gemm_kernel<<<dim3(NTOK / 64, D_INNER / 64), 256, 0, stream>>>(
        xdbl, dtw_b, dtb, dtq);

    // K5: chunked parallel scan, NCH=64 (4 blocks/CU), bf16-packed stitch
    scan_partA_kernel<<<1024, 256, 0, stream>>>(dtq, xcb, xdbl, alog, ch);
    scan_partB_kernel<<<256, 256, 0, stream>>>(ch, hinit);
    scan_partC_kernel<<<1024, 256, 0, stream>>>(dtq, xcb, xdbl, zq,
                                                alog, dvec, hinit, yg_bf16);

    // K6: out = yg @ out_proj_w^T, 64x64 split-K=2 (1024 blocks = 4/CU)
    gemm64_kernel<<<dim3(NTOK / 64, D_MODEL / 64, 2), 256, 0, stream>>>(
        yg_bf16, wOut, out_main, NTOK, D_MODEL, D_INNER);
}

// Round 15
// 227.875 us; speedup vs baseline: 2.1183x; 1.0330x over previous
//
#include <hip/hip_runtime.h>

// ---------- common helpers ----------
typedef __bf16 bf16x8 __attribute__((ext_vector_type(8)));
typedef float f32x4 __attribute__((ext_vector_type(4)));

__device__ __forceinline__ float b2f(ushort u) {
    union { unsigned int i; float f; } v;
    v.i = ((unsigned int)u) << 16;
    return v.f;
}
__device__ __forceinline__ ushort f2b(float f) {
    union { float f; unsigned int i; } v;
    v.f = f;
    unsigned int x = v.i;
    unsigned int r = (x + 0x7fffu + ((x >> 16) & 1u)) >> 16;
    return (ushort)r;
}
__device__ __forceinline__ float fexp2(float x) {
#if __has_builtin(__builtin_amdgcn_exp2f)
    return __builtin_amdgcn_exp2f(x);
#else
    return exp2f(x);
#endif
}
// pack (ap,h) as bf16 pair: lo=ap, hi=h
__device__ __forceinline__ unsigned int packb2(float ap, float h) {
    return ((unsigned int)f2b(h) << 16) | (unsigned int)f2b(ap);
}
// async 16B global->LDS; lane i lands at lds + i*16B (wave-uniform base)
__device__ __forceinline__ void gload16(const ushort* g, ushort* l) {
    __builtin_amdgcn_global_load_lds(
        (const __attribute__((address_space(1))) unsigned int*)g,
        (__attribute__((address_space(3))) unsigned int*)l, 16, 0, 0);
}
// LDS fragment read with XOR chunk swizzle (row stride 64 ushorts, 8 chunks of 8)
__device__ __forceinline__ bf16x8 ldsfrag(const ushort* s, int row, int cq) {
    int p = cq ^ (row & 7);
    return *(const bf16x8*)(s + row * 64 + p * 8);
}

#define D_MODEL 1024
#define D_INNER 2048
#define D_STATE 16
#define DT_RANK 64
#define NTOK    2048   // B*L
#define LSEQ    1024
#define NCH     64     // scan chunks (64: 4 blocks/CU for latency hiding)
#define LC      16     // steps per chunk
#define KSL     16     // xproj K-slices
#define LOG2E   1.44269504088896f

// ---------- K0: prep = RMSNorm + weight cvts + xdbl zero ----------
__global__ __launch_bounds__(256) void prep_kernel(
    const float* __restrict__ hs, const float* __restrict__ w,
    ushort* __restrict__ hout, float* __restrict__ resid,
    const float* __restrict__ inproj, const float* __restrict__ outproj,
    const float* __restrict__ xprojw, const float* __restrict__ dtw,
    ushort* __restrict__ wIn, ushort* __restrict__ wOut,
    ushort* __restrict__ xpw, ushort* __restrict__ dtwb,
    float* __restrict__ xdbl)
{
    int blk = blockIdx.x;
    int tid = threadIdx.x;
    if (blk < NTOK) {
        int t = blk;
        float4 r4 = *(const float4*)(hs + (size_t)t * D_MODEL + tid * 4);
        float s = r4.x * r4.x + r4.y * r4.y + r4.z * r4.z + r4.w * r4.w;
        #pragma unroll
        for (int off = 32; off >= 1; off >>= 1) s += __shfl_xor(s, off);
        __shared__ float red[4];
        int lane = tid & 63, wid = tid >> 6;
        if (lane == 0) red[wid] = s;
        __syncthreads();
        float tot = red[0] + red[1] + red[2] + red[3];
        float inv = 1.0f / (sqrtf(tot) * (1.0f / 32.0f) + 1e-5f);
        float4 w4 = *(const float4*)(w + tid * 4);
        ushort4 o;
        o.x = f2b(w4.x * r4.x * inv);
        o.y = f2b(w4.y * r4.y * inv);
        o.z = f2b(w4.z * r4.z * inv);
        o.w = f2b(w4.w * r4.w * inv);
        *(ushort4*)(hout + (size_t)t * D_MODEL + tid * 4) = o;
        *(float4*)(resid + (size_t)t * D_MODEL + tid * 4) = r4;   // exact copy
    } else if (blk < NTOK + 6464) {
        int i = (blk - NTOK) * 256 + tid;
        const float* src; ushort* dst; int off;
        if (i < 1048576)      { src = inproj;  dst = wIn;  off = i; }
        else if (i < 1572864) { src = outproj; dst = wOut; off = i - 1048576; }
        else if (i < 1622016) { src = xprojw;  dst = xpw;  off = i - 1572864; }
        else if (i < 1654784) { src = dtw;     dst = dtwb; off = i - 1622016; }
        else return;
        float4 v = *(const float4*)(src + (size_t)off * 4);
        ushort4 o;
        o.x = f2b(v.x); o.y = f2b(v.y); o.z = f2b(v.z); o.w = f2b(v.w);
        *(ushort4*)(dst + (size_t)off * 4) = o;
    } else {
        int i = (blk - NTOK - 6464) * 256 + tid;   // 49152 float4s = 196608 floats
        if (i < 49152)
            *(float4*)(xdbl + (size_t)i * 4) = (float4){0.f, 0.f, 0.f, 0.f};
    }
}

// ---------- K2: xz GEMM 128x128, 8 waves (512 thr), fused conv/SiLU epilogue ----------
// bn<16: x-half -> conv+SiLU rows 3..127 written to xcb; raw boundary rows
//        {0,1,2,125,126,127} saved to xb for the fixup kernel.
// bn>=16: z-half -> plain bf16 store to zq (LDS-repack coalesced).
// 8 waves/block -> 2 blocks/CU = 4 waves/SIMD: hides barrier drain.
__global__ __launch_bounds__(512) void gemm_xz_kernel(
    const ushort* __restrict__ Ag, const ushort* __restrict__ Wg,
    const float* __restrict__ cw, const float* __restrict__ cb,
    ushort* __restrict__ xcb, ushort* __restrict__ xb,
    ushort* __restrict__ zq, int K)
{
    __shared__ __align__(16) ushort smem[128 * 128];   // 32KB: staging + C repack
    __shared__ float cwl[128][4];
    __shared__ float cbl[128];
    ushort* sA = smem;
    ushort* sB = smem + 128 * 64;
    int tid = threadIdx.x;
    int bm = blockIdx.x, bn = blockIdx.y;
    int wid = tid >> 6, lane = tid & 63;
    int wm = (wid >> 1) * 32, wn = (wid & 1) * 64;   // wave owns 32x64
    int l16 = lane & 15, q = lane >> 4;
    int colbase = (bn & 15) * 128;

    if (bn < 16 && tid < 128) {            // stage conv weights for this col range
        cwl[tid][0] = cw[(size_t)(colbase + tid) * 4 + 0];
        cwl[tid][1] = cw[(size_t)(colbase + tid) * 4 + 1];
        cwl[tid][2] = cw[(size_t)(colbase + tid) * 4 + 2];
        cwl[tid][3] = cw[(size_t)(colbase + tid) * 4 + 3];
        cbl[tid] = cb[colbase + tid];
    }

    f32x4 acc[2][4];
    #pragma unroll
    for (int i = 0; i < 2; i++)
        #pragma unroll
        for (int j = 0; j < 4; j++)
            acc[i][j] = (f32x4){0.f, 0.f, 0.f, 0.f};

    const ushort* Abase = Ag + (size_t)bm * 128 * K;
    const ushort* Wbase = Wg + (size_t)bn * 128 * K;

    int segr = lane >> 3, segc = lane & 7;
    size_t goff[2]; int sseg[2];
    #pragma unroll
    for (int t = 0; t < 2; t++) {          // 16 segs each for A and B, 8 wids x 2
        int s = wid * 2 + t;
        int r = s * 8 + segr;
        int gc = segc ^ (r & 7);
        sseg[t] = s * 512;
        goff[t] = (size_t)r * K + gc * 8;
    }

    for (int k0 = 0; k0 < K; k0 += 64) {
        __syncthreads();
        #pragma unroll
        for (int t = 0; t < 2; t++) {
            gload16(Abase + goff[t] + k0, sA + sseg[t]);
            gload16(Wbase + goff[t] + k0, sB + sseg[t]);
        }
        __syncthreads();
        #pragma unroll
        for (int ks = 0; ks < 2; ks++) {
            int cq = ks * 4 + q;
            bf16x8 af[2], bfr[4];
            #pragma unroll
            for (int i = 0; i < 2; i++)
                af[i] = ldsfrag(sA, wm + i * 16 + l16, cq);
            #pragma unroll
            for (int j = 0; j < 4; j++)
                bfr[j] = ldsfrag(sB, wn + j * 16 + l16, cq);
            #pragma unroll
            for (int i = 0; i < 2; i++)
                #pragma unroll
                for (int j = 0; j < 4; j++)
                    acc[i][j] = __builtin_amdgcn_mfma_f32_16x16x32_bf16(af[i], bfr[j], acc[i][j], 0, 0, 0);
        }
    }

    // repack bf16 C tile into LDS (chunk-XOR vs row to spread banks)
    __syncthreads();
    #pragma unroll
    for (int i = 0; i < 2; i++)
        #pragma unroll
        for (int j = 0; j < 4; j++) {
            int col = wn + j * 16 + l16;
            int cchunk = col >> 3, cin = col & 7;
            #pragma unroll
            for (int r = 0; r < 4; r++) {
                int row = wm + i * 16 + q * 4 + r;
                smem[row * 128 + ((cchunk ^ (row & 7)) << 3) + cin] =
                    f2b(acc[i][j][r]);
            }
        }
    __syncthreads();
    size_t rowbase = (size_t)bm * 128;

    if (bn >= 16) {                        // z-half: plain coalesced store
        int cb2 = (bn - 16) * 128;
        #pragma unroll
        for (int it = 0; it < 4; it++) {
            int flat = it * 4096 + tid * 8;
            int row = flat >> 7, cchunk = (flat & 127) >> 3;
            *(uint4*)(zq + (rowbase + row) * D_INNER + cb2 + (cchunk << 3)) =
                *(const uint4*)(smem + row * 128 + ((cchunk ^ (row & 7)) << 3));
        }
        return;
    }

    // x-half: save raw boundary rows {0,1,2,125,126,127} for the fixup kernel
    if (tid < 96) {
        int rr = tid >> 4;                 // 0..5
        int row = (rr < 3) ? rr : (125 + rr - 3);
        int chunk = tid & 15;
        *(uint4*)(xb + (size_t)(bm * 6 + rr) * D_INNER + colbase + chunk * 8) =
            *(const uint4*)(smem + row * 128 + ((chunk ^ (row & 7)) << 3));
    }

    // fused conv+SiLU for rows 3..127 (l>=3 guaranteed: l=(bm&7)*128+row)
    for (int idx = tid; idx < 2000; idx += 512) {
        int row = (idx >> 4) + 3;
        int chunk = idx & 15;
        ushort tap[4][8];
        #pragma unroll
        for (int k = 0; k < 4; k++) {
            int rk = row - 3 + k;
            *(uint4*)tap[k] =
                *(const uint4*)(smem + rk * 128 + ((chunk ^ (rk & 7)) << 3));
        }
        ushort o[8];
        #pragma unroll
        for (int j = 0; j < 8; j++) {
            int cl = chunk * 8 + j;
            float acc2 = cbl[cl];
            #pragma unroll
            for (int k = 0; k < 4; k++)
                acc2 += b2f(tap[k][j]) * cwl[cl][k];
            o[j] = f2b(acc2 / (1.f + __expf(-acc2)));
        }
        *(uint4*)(xcb + (rowbase + row) * D_INNER + colbase + chunk * 8) =
            *(const uint4*)o;
    }
}

// ---------- K2b: conv fixup for rows 0..2 of each 128-token tile (48 tokens) ----------
__global__ __launch_bounds__(256) void conv_fixup_kernel(
    const ushort* __restrict__ xb, const float* __restrict__ cw,
    const float* __restrict__ cb, ushort* __restrict__ xcb)
{
    int bm = blockIdx.x / 3;               // 0..15
    int r  = blockIdx.x % 3;               // 0..2
    int d0 = threadIdx.x * 8;

    ushort tap[4][8];
    bool has[4];
    #pragma unroll
    for (int k = 0; k < 4; k++) {
        int rt = r - 3 + k;                // token offset within tile, may be <0
        if (rt < 0 && (bm & 7) == 0) {     // l = r here -> causal zero-pad
            has[k] = false;
        } else {
            has[k] = true;
            int bmm, slot;
            if (rt < 0) { bmm = bm - 1; slot = rt + 6; }   // prev rows 125..127 -> 3..5
            else        { bmm = bm;     slot = rt; }       // own rows 0..2
            *(uint4*)tap[k] =
                *(const uint4*)(xb + (size_t)(bmm * 6 + slot) * D_INNER + d0);
        }
    }
    ushort o[8];
    #pragma unroll
    for (int j = 0; j < 8; j++) {
        float4 w4 = *(const float4*)(cw + (size_t)(d0 + j) * 4);
        float wk[4] = {w4.x, w4.y, w4.z, w4.w};
        float acc = cb[d0 + j];
        #pragma unroll
        for (int k = 0; k < 4; k++)
            if (has[k]) acc += b2f(tap[k][j]) * wk[k];
        o[j] = f2b(acc / (1.f + __expf(-acc)));
    }
    *(uint4*)(xcb + (size_t)(bm * 128 + r) * D_INNER + d0) = *(const uint4*)o;
}

// ---------- K6: 64x64 GEMM, BK=64, async + XOR swizzle, LDS-repack epilogue ----------
__global__ __launch_bounds__(256) void gemm64_kernel(
    const ushort* __restrict__ Ag, const ushort* __restrict__ Wg,
    float* __restrict__ Cf, int M, int N, int K)
{
    __shared__ __align__(16) ushort smem[64 * 128];   // 16KB: staging + f32 C repack
    ushort* sA = smem;
    ushort* sB = smem + 64 * 64;
    float* fs = (float*)smem;
    int tid = threadIdx.x;
    int bm = blockIdx.x, bn = blockIdx.y;
    int wid = tid >> 6, lane = tid & 63;
    int wm = wid * 16;
    int l16 = lane & 15, q = lane >> 4;

    f32x4 acc[4];
    #pragma unroll
    for (int j = 0; j < 4; j++) acc[j] = (f32x4){0.f, 0.f, 0.f, 0.f};

    const ushort* Abase = Ag + (size_t)bm * 64 * K;
    const ushort* Wbase = Wg + (size_t)bn * 64 * K;

    int segr = lane >> 3, segc = lane & 7;
    size_t goff[2]; int sseg[2];
    #pragma unroll
    for (int t = 0; t < 2; t++) {
        int s = wid * 2 + t;
        int r = s * 8 + segr;
        int gc = segc ^ (r & 7);
        sseg[t] = s * 512;
        goff[t] = (size_t)r * K + gc * 8;
    }

    for (int k0 = 0; k0 < K; k0 += 64) {
        __syncthreads();
        #pragma unroll
        for (int t = 0; t < 2; t++) {
            gload16(Abase + goff[t] + k0, sA + sseg[t]);
            gload16(Wbase + goff[t] + k0, sB + sseg[t]);
        }
        __syncthreads();
        #pragma unroll
        for (int ks = 0; ks < 2; ks++) {
            int cq = ks * 4 + q;
            bf16x8 af = ldsfrag(sA, wm + l16, cq);
            bf16x8 bfr[4];
            #pragma unroll
            for (int j = 0; j < 4; j++)
                bfr[j] = ldsfrag(sB, j * 16 + l16, cq);
            #pragma unroll
            for (int j = 0; j < 4; j++)
                acc[j] = __builtin_amdgcn_mfma_f32_16x16x32_bf16(af, bfr[j], acc[j], 0, 0, 0);
        }
    }

    __syncthreads();
    #pragma unroll
    for (int j = 0; j < 4; j++)
        #pragma unroll
        for (int r = 0; r < 4; r++)
            fs[(wm + q * 4 + r) * 64 + j * 16 + l16] = acc[j][r];
    __syncthreads();
    #pragma unroll
    for (int it = 0; it < 4; it++) {
        int flat = it * 1024 + tid * 4;              // float index in 64x64 tile
        int row = flat >> 6, col = flat & 63;
        *(float4*)(Cf + (size_t)(bm * 64 + row) * N + bn * 64 + col) =
            *(const float4*)(fs + row * 64 + col);
    }
}

// ---------- K4a: xproj split-K partial GEMM, atomic accumulate into xdbl ----------
// LDS row stride 40 ushorts (80B, 16B-aligned): ~2-way banks vs 8-way at 32
__global__ __launch_bounds__(256) void xproj_partial_kernel(
    const ushort* __restrict__ xcb, const ushort* __restrict__ wq,
    float* __restrict__ xdbl)
{
    __shared__ __align__(16) ushort sA[128 * 40];
    __shared__ __align__(16) ushort sB[96 * 40];
    int tid = threadIdx.x;
    int bm = blockIdx.x, sl = blockIdx.y;
    int wid = tid >> 6, lane = tid & 63;
    int wm = wid * 32;
    int l16 = lane & 15, q = lane >> 4;

    f32x4 acc[2][6];
    #pragma unroll
    for (int i = 0; i < 2; i++)
        #pragma unroll
        for (int j = 0; j < 6; j++)
            acc[i][j] = (f32x4){0.f, 0.f, 0.f, 0.f};

    const ushort* Abase = xcb + (size_t)bm * 128 * D_INNER;
    int kbase = sl * (D_INNER / KSL);

    for (int kk = 0; kk < D_INNER / KSL; kk += 32) {
        int k0 = kbase + kk;
        __syncthreads();
        #pragma unroll
        for (int i = tid; i < 512; i += 256) {
            int r = i >> 2, c = (i & 3) << 3;
            *(uint4*)(sA + r * 40 + c) = *(const uint4*)(Abase + (size_t)r * D_INNER + k0 + c);
        }
        for (int i = tid; i < 384; i += 256) {
            int r = i >> 2, c = (i & 3) << 3;
            *(uint4*)(sB + r * 40 + c) = *(const uint4*)(wq + (size_t)r * D_INNER + k0 + c);
        }
        __syncthreads();
        bf16x8 af[2], bfr[6];
        #pragma unroll
        for (int i = 0; i < 2; i++)
            af[i] = *(const bf16x8*)(sA + (wm + i * 16 + l16) * 40 + q * 8);
        #pragma unroll
        for (int j = 0; j < 6; j++)
            bfr[j] = *(const bf16x8*)(sB + (j * 16 + l16) * 40 + q * 8);
        #pragma unroll
        for (int i = 0; i < 2; i++)
            #pragma unroll
            for (int j = 0; j < 6; j++)
                acc[i][j] = __builtin_amdgcn_mfma_f32_16x16x32_bf16(af[i], bfr[j], acc[i][j], 0, 0, 0);
    }

    int row0 = bm * 128 + wm + q * 4;
    #pragma unroll
    for (int i = 0; i < 2; i++)
        #pragma unroll
        for (int j = 0; j < 6; j++)
            #pragma unroll
            for (int r = 0; r < 4; r++)
                atomicAdd(&xdbl[(size_t)(row0 + i * 16 + r) * 96 + j * 16 + l16],
                          acc[i][j][r]);
}

// ---------- K4b: dt = softplus(xdbl[:, :64] @ dt_proj_w^T + b) -> bf16 ----------
__global__ __launch_bounds__(256) void dt_gemm_kernel(
    const float* __restrict__ xdbl, const ushort* __restrict__ dtwq,
    const float* __restrict__ dtb, ushort* __restrict__ dtout)
{
    __shared__ __align__(16) ushort sA[64 * 72];
    __shared__ __align__(16) ushort sB[64 * 72];
    int tid = threadIdx.x;
    int bm = blockIdx.x, bn = blockIdx.y;
    int wid = tid >> 6, lane = tid & 63;
    int wm = wid * 16;
    int l16 = lane & 15, q = lane >> 4;

    const float* Abase = xdbl + (size_t)bm * 64 * 96;
    const ushort* Bbase = dtwq + (size_t)bn * 64 * DT_RANK;
    #pragma unroll
    for (int i = tid; i < 512; i += 256) {
        int r = i >> 3, c = (i & 7) << 3;
        float4 v0 = *(const float4*)(Abase + (size_t)r * 96 + c);
        float4 v1 = *(const float4*)(Abase + (size_t)r * 96 + c + 4);
        ushort o[8] = {f2b(v0.x), f2b(v0.y), f2b(v0.z), f2b(v0.w),
                       f2b(v1.x), f2b(v1.y), f2b(v1.z), f2b(v1.w)};
        *(uint4*)(sA + r * 72 + c) = *(const uint4*)o;
        *(uint4*)(sB + r * 72 + c) = *(const uint4*)(Bbase + (size_t)r * DT_RANK + c);
    }
    __syncthreads();

    f32x4 acc[4];
    #pragma unroll
    for (int j = 0; j < 4; j++) acc[j] = (f32x4){0.f, 0.f, 0.f, 0.f};

    #pragma unroll
    for (int ks = 0; ks < 2; ks++) {
        bf16x8 af = *(const bf16x8*)(sA + (wm + l16) * 72 + ks * 32 + q * 8);
        bf16x8 bfr[4];
        #pragma unroll
        for (int j = 0; j < 4; j++)
            bfr[j] = *(const bf16x8*)(sB + (j * 16 + l16) * 72 + ks * 32 + q * 8);
        #pragma unroll
        for (int j = 0; j < 4; j++)
            acc[j] = __builtin_amdgcn_mfma_f32_16x16x32_bf16(af, bfr[j], acc[j], 0, 0, 0);
    }

    __syncthreads();
    #pragma unroll
    for (int j = 0; j < 4; j++) {
        float bias = dtb[bn * 64 + j * 16 + l16];
        #pragma unroll
        for (int r = 0; r < 4; r++) {
            float s = acc[j][r] + bias;
            float sp = (s > 20.f) ? s : log1pf(__expf(s));
            sA[(wm + q * 4 + r) * 72 + j * 16 + l16] = f2b(sp);
        }
    }
    __syncthreads();
    int row0 = bm * 64, col0 = bn * 64;
    #pragma unroll
    for (int rep = 0; rep < 2; rep++) {
        int off = rep * 2048 + tid * 8;
        int row = off >> 6, col = off & 63;
        *(uint4*)(dtout + (size_t)(row0 + row) * D_INNER + col0 + col) =
            *(const uint4*)(sA + row * 72 + col);
    }
}

// ---------- K5a: scan pass A — lane-owns-d, NCH=64, bf16-packed (ap,h) ----------
__global__ __launch_bounds__(256) void scan_partA_kernel(
    const ushort* __restrict__ dt, const ushort* __restrict__ xcq,
    const float* __restrict__ xdbl, const float* __restrict__ Alog,
    unsigned int* __restrict__ ch)
{
    __shared__ float sBC[LC][32];
    int bid = blockIdx.x;                  // 1024 = b(2) x chunk(64) x dgroup(8)
    int g = bid & 7;
    int c = (bid >> 3) & (NCH - 1);
    int b = bid >> 9;
    int tid = threadIdx.x;
    int lane = tid & 63, wid = tid >> 6;
    int d = g * 256 + wid * 64 + lane;
    int l0 = c * LC;

    if (tid < LC * 8) {                    // stage B/C tile (16 rows x 32 floats)
        int r = tid >> 3, c4 = (tid & 7) * 4;
        *(float4*)&sBC[r][c4] =
            *(const float4*)(xdbl + ((size_t)(b * LSEQ + l0 + r)) * 96 + 64 + c4);
    }
    float A[16];
    #pragma unroll
    for (int k = 0; k < 4; k++)
        *(float4*)&A[k * 4] = *(const float4*)(Alog + d * D_STATE + k * 4);
    #pragma unroll
    for (int n = 0; n < 16; n++) A[n] = -__expf(A[n]) * LOG2E;
    __syncthreads();

    const ushort* dtp = dt  + ((size_t)(b * LSEQ + l0)) * D_INNER + d;
    const ushort* xcp = xcq + ((size_t)(b * LSEQ + l0)) * D_INNER + d;

    float h[16];
    #pragma unroll
    for (int n = 0; n < 16; n++) h[n] = 0.f;
    float S = 0.f;                         // sum of dtv; prod a = exp2(A*S)

    for (int l = 0; l < LC; l++) {
        float dtv = b2f(dtp[(size_t)l * D_INNER]);
        float xcv = b2f(xcp[(size_t)l * D_INNER]);
        float t = dtv * xcv;
        S += dtv;
        float Bv[16];
        #pragma unroll
        for (int k = 0; k < 4; k++)
            *(float4*)&Bv[k * 4] = *(const float4*)&sBC[l][k * 4];
        #pragma unroll
        for (int n = 0; n < 16; n++) {
            float a = fexp2(dtv * A[n]);
            h[n] = h[n] * a + t * Bv[n];
        }
    }

    unsigned int* outp = ch + (((size_t)(c * 2 + b)) << 15) + (d << 4);
    #pragma unroll
    for (int n = 0; n < 16; n += 4) {
        uint4 v;
        v.x = packb2(fexp2(A[n] * S),     h[n]);
        v.y = packb2(fexp2(A[n + 1] * S), h[n + 1]);
        v.z = packb2(fexp2(A[n + 2] * S), h[n + 2]);
        v.w = packb2(fexp2(A[n + 3] * S), h[n + 3]);
        *(uint4*)&outp[n] = v;
    }
}

// ---------- K5b: stitch — bf16 ch in, bf16 h_init out ----------
__global__ __launch_bounds__(256) void scan_partB_kernel(
    const unsigned int* __restrict__ ch, ushort* __restrict__ hinit)
{
    int kk = blockIdx.x * 256 + threadIdx.x;   // 65536 = b(2) x dn(32768)
    int b = kk >> 15, dn = kk & 32767;
    float run = 0.f;
    #pragma unroll 8
    for (int c = 0; c < NCH; c++) {
        size_t off = (((size_t)(c * 2 + b)) << 15) + dn;
        unsigned int v = ch[off];
        hinit[off] = f2b(run);
        run = b2f((ushort)(v & 0xffffu)) * run + b2f((ushort)(v >> 16));
    }
}

// ---------- K5c: scan pass C — lane-owns-d, fused C-proj + D-skip + gate ----------
__global__ __launch_bounds__(256) void scan_partC_kernel(
    const ushort* __restrict__ dt, const ushort* __restrict__ xcq,
    const float* __restrict__ xdbl, const ushort* __restrict__ zq,
    const float* __restrict__ Alog, const float* __restrict__ Dp,
    const ushort* __restrict__ hinit, ushort* __restrict__ yg)
{
    __shared__ float sBC[LC][32];
    int bid = blockIdx.x;
    int g = bid & 7;
    int c = (bid >> 3) & (NCH - 1);
    int b = bid >> 9;
    int tid = threadIdx.x;
    int lane = tid & 63, wid = tid >> 6;
    int d = g * 256 + wid * 64 + lane;
    int l0 = c * LC;

    if (tid < LC * 8) {
        int r = tid >> 3, c4 = (tid & 7) * 4;
        *(float4*)&sBC[r][c4] =
            *(const float4*)(xdbl + ((size_t)(b * LSEQ + l0 + r)) * 96 + 64 + c4);
    }
    float A[16];
    #pragma unroll
    for (int k = 0; k < 4; k++)
        *(float4*)&A[k * 4] = *(const float4*)(Alog + d * D_STATE + k * 4);
    #pragma unroll
    for (int n = 0; n < 16; n++) A[n] = -__expf(A[n]) * LOG2E;
    float Dd = Dp[d];

    const ushort* hp = hinit + (((size_t)(c * 2 + b)) << 15) + (d << 4);
    float h[16];
    #pragma unroll
    for (int n = 0; n < 16; n += 4) {
        ushort4 v = *(const ushort4*)(hp + n);
        h[n] = b2f(v.x); h[n + 1] = b2f(v.y);
        h[n + 2] = b2f(v.z); h[n + 3] = b2f(v.w);
    }
    __syncthreads();

    const ushort* dtp = dt  + ((size_t)(b * LSEQ + l0)) * D_INNER + d;
    const ushort* xcp = xcq + ((size_t)(b * LSEQ + l0)) * D_INNER + d;
    const ushort* zp  = zq  + ((size_t)(b * LSEQ + l0)) * D_INNER + d;
    ushort* yp = yg + ((size_t)(b * LSEQ + l0)) * D_INNER + d;

    for (int l = 0; l < LC; l++) {
        float dtv = b2f(dtp[(size_t)l * D_INNER]);
        float xcv = b2f(xcp[(size_t)l * D_INNER]);
        float zv  = b2f(zp[(size_t)l * D_INNER]);
        float t = dtv * xcv;
        float Bv[16], Cv[16];
        #pragma unroll
        for (int k = 0; k < 4; k++) {
            *(float4*)&Bv[k * 4] = *(const float4*)&sBC[l][k * 4];
            *(float4*)&Cv[k * 4] = *(const float4*)&sBC[l][16 + k * 4];
        }
        float p0 = 0.f, p1 = 0.f, p2 = 0.f, p3 = 0.f;
        #pragma unroll
        for (int n = 0; n < 16; n += 4) {
            float a0 = fexp2(dtv * A[n]);
            float a1 = fexp2(dtv * A[n + 1]);
            float a2 = fexp2(dtv * A[n + 2]);
            float a3 = fexp2(dtv * A[n + 3]);
            h[n]     = h[n] * a0 + t * Bv[n];
            h[n + 1] = h[n + 1] * a1 + t * Bv[n + 1];
            h[n + 2] = h[n + 2] * a2 + t * Bv[n + 2];
            h[n + 3] = h[n + 3] * a3 + t * Bv[n + 3];
            p0 += h[n] * Cv[n];
            p1 += h[n + 1] * Cv[n + 1];
            p2 += h[n + 2] * Cv[n + 2];
            p3 += h[n + 3] * Cv[n + 3];
        }
        float p = (p0 + p1) + (p2 + p3);
        float y = p + Dd * xcv;
        float sz = zv / (1.f + __expf(-zv));
        yp[(size_t)l * D_INNER] = f2b(y * sz);
    }
}

extern "C" void kernel_launch(void* const* d_in, const int* in_sizes, int n_in,
                              void* d_out, int out_size, void* d_ws, size_t ws_size,
                              hipStream_t stream)
{
    const float* hs      = (const float*)d_in[0];
    const float* norm_w  = (const float*)d_in[1];
    const float* inproj  = (const float*)d_in[2];
    const float* convw   = (const float*)d_in[3];
    const float* convb   = (const float*)d_in[4];
    const float* xprojw  = (const float*)d_in[5];
    const float* dtw     = (const float*)d_in[6];
    const float* dtb     = (const float*)d_in[7];
    const float* alog    = (const float*)d_in[8];
    const float* dvec    = (const float*)d_in[9];
    const float* outproj = (const float*)d_in[10];

    float* out_main  = (float*)d_out;
    float* out_resid = (float*)d_out + (size_t)NTOK * D_MODEL;

    char* ws = (char*)d_ws;
    ushort*       xb    = (ushort*)(ws);                     // 384KB boundary rows
    ushort*       zq    = (ushort*)(ws +  8388608);          // 8.4MB
    ushort*       dtq   = (ushort*)(ws + 16777216);          // 8.4MB
    ushort*       xcb   = (ushort*)(ws + 25165824);          // 8.4MB
    unsigned int* ch    = (unsigned int*)(ws + 33554432);    // 16.8MB (bf16 ap,h)
    ushort*       hinit = (ushort*)(ws + 50331648);          // 8.4MB (bf16 h_init)
    float*        xdbl  = (float*) (ws + 67108864);          // 768KB
    ushort*       wIn   = (ushort*)(ws + 67895296);          // 8.4MB
    ushort*       wOut  = (ushort*)(ws + 76283904);          // 4.2MB
    ushort*       h_bf16= (ushort*)(ws + 80478208);          // 4.2MB
    ushort*       xpw_b = (ushort*)(ws + 84672512);          // 384KB
    ushort*       dtw_b = (ushort*)(ws + 85065728);          // 256KB
    ushort*       yg_bf16=(ushort*)(ws + 85327872);          // 8.4MB (end ~93.7MB)

    // K0: prep = rmsnorm + weight cvts + xdbl zero
    prep_kernel<<<NTOK + 6464 + 192, 256, 0, stream>>>(
        hs, norm_w, h_bf16, out_resid,
        inproj, outproj, xprojw, dtw, wIn, wOut, xpw_b, dtw_b, xdbl);

    // K2: xz GEMM (512 thr, 8 waves) + fused conv/SiLU (x-half) -> xcb, zq, xb
    gemm_xz_kernel<<<dim3(NTOK / 128, (2 * D_INNER) / 128), 512, 0, stream>>>(
        h_bf16, wIn, convw, convb, xcb, xb, zq, D_MODEL);

    // K2b: finish conv for first 3 rows of each 128-token tile
    conv_fixup_kernel<<<48, 256, 0, stream>>>(xb, convw, convb, xcb);

    // K4a: x_dbl GEMM — split-K, atomic accumulate into zeroed xdbl
    xproj_partial_kernel<<<dim3(NTOK / 128, KSL), 256, 0, stream>>>(
        xcb, xpw_b, xdbl);

    // K4b: dt GEMM (A staged from f32 xdbl) + bias + softplus -> bf16
    dt_gemm_kernel<<<dim3(NTOK / 64, D_INNER / 64), 256, 0, stream>>>(
        xdbl, dtw_b, dtb, dtq);

    // K5: chunked parallel scan, NCH=64 (4 blocks/CU), bf16-packed stitch
    scan_partA_kernel<<<1024, 256, 0, stream>>>(dtq, xcb, xdbl, alog, ch);
    scan_partB_kernel<<<256, 256, 0, stream>>>(ch, hinit);
    scan_partC_kernel<<<1024, 256, 0, stream>>>(dtq, xcb, xdbl, zq,
                                                alog, dvec, hinit, yg_bf16);

    // K6: out = yg @ out_proj_w^T -> f32 (64x64, LDS-repack epilogue)
    gemm64_kernel<<<dim3(NTOK / 64, D_MODEL / 64), 256, 0, stream>>>(
        yg_bf16, wOut, out_main, NTOK, D_MODEL, D_INNER);
}